// Round 1
// baseline (1375.955 us; speedup 1.0000x reference)
//
#include <hip/hip_runtime.h>
#include <math.h>

#define B_ 2
#define S_ 2048
#define D_ 1024
#define H_ 16
#define DK_ 64
#define V_ 4096
#define NZ_ 10
#define NT_ 32            // S_/64 tiles of v rows
#define NEG9 -1.0e9f

// ---------------------------------------------------------------------------
// GEMM: C[M,N] = A[M,K] * W[N,K]^T + bias[N]   (both A and W row-major,
// inner dim K contiguous -> dot of A-row with W-row)
// ---------------------------------------------------------------------------
template <int BM, int BN, int BK>
__global__ __launch_bounds__(256) void gemm_bias(const float* __restrict__ A,
                                                 const float* __restrict__ W,
                                                 const float* __restrict__ bias,
                                                 float* __restrict__ C,
                                                 int M, int N, int K) {
  __shared__ float As[BK][BM + 1];
  __shared__ float Ws[BK][BN + 1];
  const int t = threadIdx.x;
  const int bm = blockIdx.y, bn = blockIdx.x;
  const int tx = t & 15, ty = t >> 4;
  const int lr = t >> 2;          // 0..63: row within tile
  const int lk = (t & 3) << 2;    // 0,4,8,12: k within tile
  const float* Ap = A + (size_t)(bm * BM + lr) * K + lk;
  const float* Wp = W + (size_t)(bn * BN + lr) * K + lk;
  float acc[4][4] = {};
  for (int k0 = 0; k0 < K; k0 += BK) {
    float4 a4 = *(const float4*)(Ap + k0);
    float4 w4 = *(const float4*)(Wp + k0);
    __syncthreads();   // previous iteration's reads complete before overwrite
    As[lk + 0][lr] = a4.x; As[lk + 1][lr] = a4.y;
    As[lk + 2][lr] = a4.z; As[lk + 3][lr] = a4.w;
    Ws[lk + 0][lr] = w4.x; Ws[lk + 1][lr] = w4.y;
    Ws[lk + 2][lr] = w4.z; Ws[lk + 3][lr] = w4.w;
    __syncthreads();
#pragma unroll
    for (int kk = 0; kk < BK; ++kk) {
      float a[4], bv[4];
#pragma unroll
      for (int i = 0; i < 4; ++i) a[i] = As[kk][ty * 4 + i];
#pragma unroll
      for (int j = 0; j < 4; ++j) bv[j] = Ws[kk][tx * 4 + j];
#pragma unroll
      for (int i = 0; i < 4; ++i)
#pragma unroll
        for (int j = 0; j < 4; ++j) acc[i][j] += a[i] * bv[j];
    }
  }
#pragma unroll
  for (int i = 0; i < 4; ++i) {
    int row = bm * BM + ty * 4 + i;
#pragma unroll
    for (int j = 0; j < 4; ++j) {
      int col = bn * BN + tx * 4 + j;
      C[(size_t)row * N + col] = acc[i][j] + bias[col];
    }
  }
}

// ---------------------------------------------------------------------------
// tilesum[b][T][d] = sum over j in [64T, 64T+64) of v[b][j][d]
// ---------------------------------------------------------------------------
__global__ void tilesum_kernel(const float* __restrict__ v, float* __restrict__ ts) {
  int idx = blockIdx.x * blockDim.x + threadIdx.x;  // (b*NT_+T)*D_ + d
  int d = idx % D_;
  int bt = idx / D_;
  int T = bt % NT_;
  int b = bt / NT_;
  const float* p = v + (size_t)(b * S_ + T * 64) * D_ + d;
  float s = 0.f;
#pragma unroll 4
  for (int j = 0; j < 64; ++j) s += p[(size_t)j * D_];
  ts[idx] = s;
}

// ---------------------------------------------------------------------------
// Per (b,i): farsum[b,i,:] = sum of v rows j<=i-64 that are NOT omega-masked
// against token i; c0[b,i] = count of those rows. Uses tile sums + leftover
// rows, then subtracts the rare masked rows found by a cooperative scan.
// ---------------------------------------------------------------------------
__global__ __launch_bounds__(256) void farsum_kernel(const float* __restrict__ v,
                                                     const float* __restrict__ ts,
                                                     const int* __restrict__ ids,
                                                     const float* __restrict__ omega,
                                                     float* __restrict__ farsum,
                                                     int* __restrict__ c0) {
  const int b = blockIdx.x / S_;
  const int i = blockIdx.x % S_;
  const int t = threadIdx.x;
  if (i < 64) {
    if (t == 0) c0[blockIdx.x] = 0;
    return;
  }
  const int jmax = i - 64;   // far region: j in [0, jmax]
  const int F = jmax + 1;
  const int d0 = t * 4;
  float4 acc = make_float4(0.f, 0.f, 0.f, 0.f);
  const int nFull = F >> 6;
  for (int T = 0; T < nFull; ++T) {
    float4 x = *(const float4*)(ts + (size_t)(b * NT_ + T) * D_ + d0);
    acc.x += x.x; acc.y += x.y; acc.z += x.z; acc.w += x.w;
  }
  for (int j = nFull << 6; j <= jmax; ++j) {
    float4 x = *(const float4*)(v + (size_t)(b * S_ + j) * D_ + d0);
    acc.x += x.x; acc.y += x.y; acc.z += x.z; acc.w += x.w;
  }
  __shared__ int list[256];
  __shared__ int cnt;
  const int idi = ids[b * S_ + i];
  const float* omrow = omega + (size_t)idi * V_;
  int nmask = 0;
  for (int base = 0; base < F; base += 256) {
    if (t == 0) cnt = 0;
    __syncthreads();
    int j = base + t;
    if (j <= jmax) {
      int idj = ids[b * S_ + j];
      if (omrow[idj] == 0.f) list[atomicAdd(&cnt, 1)] = j;
    }
    __syncthreads();
    int c = cnt;
    nmask += c;
    for (int m = 0; m < c; ++m) {
      int jm = list[m];
      float4 x = *(const float4*)(v + (size_t)(b * S_ + jm) * D_ + d0);
      acc.x -= x.x; acc.y -= x.y; acc.z -= x.z; acc.w -= x.w;
    }
    __syncthreads();   // list/cnt reuse hazard
  }
  *(float4*)(farsum + (size_t)(b * S_ + i) * D_ + d0) = acc;
  if (t == 0) c0[blockIdx.x] = F - nmask;
}

// ---------------------------------------------------------------------------
// Banded attention. One block per (b,i); 4 waves; each wave handles 4 heads.
// Lane l <-> near position j = i-63+l (delta = 63-l). Far region enters via
// farsum/c0. Degenerate all-masked rows -> uniform over all S positions.
// ---------------------------------------------------------------------------
__global__ __launch_bounds__(256) void attn_kernel(const float* __restrict__ q,
                                                   const float* __restrict__ k,
                                                   const float* __restrict__ v,
                                                   const float* __restrict__ farsum,
                                                   const int* __restrict__ c0arr,
                                                   const float* __restrict__ ts,
                                                   const int* __restrict__ ids,
                                                   const float* __restrict__ omega,
                                                   const float* __restrict__ gamma,
                                                   float* __restrict__ out) {
  const int b = blockIdx.x / S_;
  const int i = blockIdx.x % S_;
  const int t = threadIdx.x;
  const int wv = t >> 6;     // wave id 0..3
  const int lane = t & 63;
  const int idi = ids[b * S_ + i];
  const int C0 = c0arr[b * S_ + i];
  const int jl = i - 63 + lane;
  const bool valid = (jl >= 0);
  const int jsafe = valid ? jl : 0;

  // memory-kernel factor for this lane's delta
  float Mfac;
  {
    float delta = (float)(63 - lane);
    float ld = logf(delta + 1.f);
    float cs = 0.f;
#pragma unroll
    for (int z = 0; z < NZ_; ++z) cs += cosf(gamma[z] * ld);
    Mfac = expf(-delta) * cs;
  }
  float omv = 1.f;
  if (valid) omv = omega[(size_t)idi * V_ + ids[b * S_ + jl]];

  for (int h = wv; h < H_; h += 4) {
    const size_t rowq = ((size_t)(b * S_) + i) * D_ + h * 64;
    float qreg = q[rowq + lane];               // lane d holds q_d
    const float* krow = k + ((size_t)(b * S_) + jsafe) * D_ + h * 64;
    float dot = 0.f;
#pragma unroll
    for (int d = 0; d < 64; d += 4) {
      float4 k4 = *(const float4*)(krow + d);
      dot += __shfl(qreg, d) * k4.x;
      dot += __shfl(qreg, d + 1) * k4.y;
      dot += __shfl(qreg, d + 2) * k4.z;
      dot += __shfl(qreg, d + 3) * k4.w;
    }
    float score;
    if (!valid) score = -INFINITY;
    else if (omv == 0.f) score = NEG9;
    else score = dot * 0.125f * Mfac;

    float m = score;
#pragma unroll
    for (int off = 32; off; off >>= 1) m = fmaxf(m, __shfl_xor(m, off));
    if (C0 > 0) m = fmaxf(m, 0.f);

    float o, denom;
    if (m < -1.0e8f) {
      // every causal position masked -> reference softmax is uniform 1/S over
      // ALL S positions (incl. future): out = mean of all v rows.
      float tv = 0.f;
      for (int T = 0; T < NT_; ++T)
        tv += ts[(size_t)(b * NT_ + T) * D_ + h * 64 + lane];
      o = tv;
      denom = (float)S_;
    } else {
      float p = valid ? expf(score - m) : 0.f;  // masked -1e9 underflows to 0
      float sum = p;
#pragma unroll
      for (int off = 32; off; off >>= 1) sum += __shfl_xor(sum, off);
      float efar = (C0 > 0) ? expf(-m) : 0.f;
      denom = sum + (float)C0 * efar;
      o = (C0 > 0) ? efar * farsum[rowq + lane] : 0.f;
#pragma unroll 4
      for (int l = 0; l < 64; ++l) {
        float pl = __shfl(p, l);
        if (pl != 0.f) {
          int j = i - 63 + l;
          o += pl * v[((size_t)(b * S_) + j) * D_ + h * 64 + lane];
        }
      }
    }
    out[rowq + lane] = o / denom;
  }
}

// ---------------------------------------------------------------------------
extern "C" void kernel_launch(void* const* d_in, const int* in_sizes, int n_in,
                              void* d_out, int out_size, void* d_ws, size_t ws_size,
                              hipStream_t stream) {
  const float* x     = (const float*)d_in[0];
  const float* wq    = (const float*)d_in[1];
  const float* bq    = (const float*)d_in[2];
  const float* wk    = (const float*)d_in[3];
  const float* bk    = (const float*)d_in[4];
  const float* wv    = (const float*)d_in[5];
  const float* bv    = (const float*)d_in[6];
  const float* wo    = (const float*)d_in[7];
  const float* bo    = (const float*)d_in[8];
  const float* omega = (const float*)d_in[9];
  const float* gamma = (const float*)d_in[10];
  const int*   ids   = (const int*)d_in[11];
  float* out = (float*)d_out;

  char* ws = (char*)d_ws;
  const size_t SZ = (size_t)B_ * S_ * D_ * sizeof(float);  // 16 MB
  float* q      = (float*)(ws);
  float* kbuf   = (float*)(ws + SZ);
  float* vbuf   = (float*)(ws + 2 * SZ);
  float* attno  = (float*)(ws + 3 * SZ);
  float* fsum   = (float*)(ws + 4 * SZ);
  float* ts     = (float*)(ws + 5 * SZ);
  int*   c0     = (int*)(ws + 5 * SZ + (size_t)B_ * NT_ * D_ * sizeof(float));

  dim3 gemmGrid(D_ / 64, (B_ * S_) / 64);
  gemm_bias<64, 64, 16><<<gemmGrid, 256, 0, stream>>>(x, wq, bq, q,    B_ * S_, D_, D_);
  gemm_bias<64, 64, 16><<<gemmGrid, 256, 0, stream>>>(x, wk, bk, kbuf, B_ * S_, D_, D_);
  gemm_bias<64, 64, 16><<<gemmGrid, 256, 0, stream>>>(x, wv, bv, vbuf, B_ * S_, D_, D_);
  tilesum_kernel<<<(B_ * NT_ * D_) / 256, 256, 0, stream>>>(vbuf, ts);
  farsum_kernel<<<B_ * S_, 256, 0, stream>>>(vbuf, ts, ids, omega, fsum, c0);
  attn_kernel<<<B_ * S_, 256, 0, stream>>>(q, kbuf, vbuf, fsum, c0, ts, ids, omega, gamma, attno);
  gemm_bias<64, 64, 16><<<gemmGrid, 256, 0, stream>>>(attno, wo, bo, out, B_ * S_, D_, D_);
}

// Round 2
// 1002.360 us; speedup vs baseline: 1.3727x; 1.3727x over previous
//
#include <hip/hip_runtime.h>
#include <math.h>
#include <float.h>

#define B_ 2
#define S_ 2048
#define D_ 1024
#define H_ 16
#define DK_ 64
#define V_ 4096
#define NZ_ 10
#define NT_ 32            // S_/64 tiles of v rows

// ---------------------------------------------------------------------------
// GEMM: C[M,N] = A[M,K] * W[N,K]^T + bias[N]
// ---------------------------------------------------------------------------
template <int BM, int BN, int BK>
__global__ __launch_bounds__(256) void gemm_bias(const float* __restrict__ A,
                                                 const float* __restrict__ W,
                                                 const float* __restrict__ bias,
                                                 float* __restrict__ C,
                                                 int M, int N, int K) {
  __shared__ float As[BK][BM + 1];
  __shared__ float Ws[BK][BN + 1];
  const int t = threadIdx.x;
  const int bm = blockIdx.y, bn = blockIdx.x;
  const int tx = t & 15, ty = t >> 4;
  const int lr = t >> 2;          // 0..63: row within tile
  const int lk = (t & 3) << 2;    // 0,4,8,12: k within tile
  const float* Ap = A + (size_t)(bm * BM + lr) * K + lk;
  const float* Wp = W + (size_t)(bn * BN + lr) * K + lk;
  float acc[4][4] = {};
  for (int k0 = 0; k0 < K; k0 += BK) {
    float4 a4 = *(const float4*)(Ap + k0);
    float4 w4 = *(const float4*)(Wp + k0);
    __syncthreads();
    As[lk + 0][lr] = a4.x; As[lk + 1][lr] = a4.y;
    As[lk + 2][lr] = a4.z; As[lk + 3][lr] = a4.w;
    Ws[lk + 0][lr] = w4.x; Ws[lk + 1][lr] = w4.y;
    Ws[lk + 2][lr] = w4.z; Ws[lk + 3][lr] = w4.w;
    __syncthreads();
#pragma unroll
    for (int kk = 0; kk < BK; ++kk) {
      float a[4], bv[4];
#pragma unroll
      for (int i = 0; i < 4; ++i) a[i] = As[kk][ty * 4 + i];
#pragma unroll
      for (int j = 0; j < 4; ++j) bv[j] = Ws[kk][tx * 4 + j];
#pragma unroll
      for (int i = 0; i < 4; ++i)
#pragma unroll
        for (int j = 0; j < 4; ++j) acc[i][j] += a[i] * bv[j];
    }
  }
#pragma unroll
  for (int i = 0; i < 4; ++i) {
    int row = bm * BM + ty * 4 + i;
#pragma unroll
    for (int j = 0; j < 4; ++j) {
      int col = bn * BN + tx * 4 + j;
      C[(size_t)row * N + col] = acc[i][j] + bias[col];
    }
  }
}

// ---------------------------------------------------------------------------
// tilesum[b][T][d] = sum over j in [64T, 64T+64) of v[b][j][d]
// ---------------------------------------------------------------------------
__global__ void tilesum_kernel(const float* __restrict__ v, float* __restrict__ ts) {
  int idx = blockIdx.x * blockDim.x + threadIdx.x;
  int d = idx % D_;
  int bt = idx / D_;
  int T = bt % NT_;
  int b = bt / NT_;
  const float* p = v + (size_t)(b * S_ + T * 64) * D_ + d;
  float s = 0.f;
#pragma unroll 4
  for (int j = 0; j < 64; ++j) s += p[(size_t)j * D_];
  ts[idx] = s;
}

// ---------------------------------------------------------------------------
// bandmask[b*S+i] bit dlt = 1 iff j=i-dlt >= 0 and omega[id_i][id_j] != 0
// ---------------------------------------------------------------------------
__global__ __launch_bounds__(256) void bandmask_kernel(const int* __restrict__ ids,
                                                       const float* __restrict__ omega,
                                                       unsigned long long* __restrict__ bm) {
  int row = blockIdx.x * 4 + (threadIdx.x >> 6);   // global (b*S + i)
  int lane = threadIdx.x & 63;
  int b = row / S_, i = row % S_;
  int idi = ids[row];
  int j = i - lane;
  bool ok = false;
  if (j >= 0) ok = omega[(size_t)idi * V_ + ids[b * S_ + j]] != 0.f;
  unsigned long long mask = __ballot(ok);
  if (lane == 0) bm[row] = mask;
}

// ---------------------------------------------------------------------------
// farsum / c0 (unchanged from round 1)
// ---------------------------------------------------------------------------
__global__ __launch_bounds__(256) void farsum_kernel(const float* __restrict__ v,
                                                     const float* __restrict__ ts,
                                                     const int* __restrict__ ids,
                                                     const float* __restrict__ omega,
                                                     float* __restrict__ farsum,
                                                     int* __restrict__ c0) {
  const int b = blockIdx.x / S_;
  const int i = blockIdx.x % S_;
  const int t = threadIdx.x;
  if (i < 64) {
    if (t == 0) c0[blockIdx.x] = 0;
    return;
  }
  const int jmax = i - 64;
  const int F = jmax + 1;
  const int d0 = t * 4;
  float4 acc = make_float4(0.f, 0.f, 0.f, 0.f);
  const int nFull = F >> 6;
  for (int T = 0; T < nFull; ++T) {
    float4 x = *(const float4*)(ts + (size_t)(b * NT_ + T) * D_ + d0);
    acc.x += x.x; acc.y += x.y; acc.z += x.z; acc.w += x.w;
  }
  for (int j = nFull << 6; j <= jmax; ++j) {
    float4 x = *(const float4*)(v + (size_t)(b * S_ + j) * D_ + d0);
    acc.x += x.x; acc.y += x.y; acc.z += x.z; acc.w += x.w;
  }
  __shared__ int list[256];
  __shared__ int cnt;
  const int idi = ids[b * S_ + i];
  const float* omrow = omega + (size_t)idi * V_;
  int nmask = 0;
  for (int base = 0; base < F; base += 256) {
    if (t == 0) cnt = 0;
    __syncthreads();
    int j = base + t;
    if (j <= jmax) {
      int idj = ids[b * S_ + j];
      if (omrow[idj] == 0.f) list[atomicAdd(&cnt, 1)] = j;
    }
    __syncthreads();
    int c = cnt;
    nmask += c;
    for (int m = 0; m < c; ++m) {
      int jm = list[m];
      float4 x = *(const float4*)(v + (size_t)(b * S_ + jm) * D_ + d0);
      acc.x -= x.x; acc.y -= x.y; acc.z -= x.z; acc.w -= x.w;
    }
    __syncthreads();
  }
  *(float4*)(farsum + (size_t)(b * S_ + i) * D_ + d0) = acc;
  if (t == 0) c0[blockIdx.x] = F - nmask;
}

// ---------------------------------------------------------------------------
// Flash-style banded attention. Block = (head, i-tile of 64 queries, batch).
// Two 64-row KV tiles (previous + diagonal); online softmax; far region via
// farsum/c0; omega via precomputed band bitmask. S aliases the K LDS buffer.
// ---------------------------------------------------------------------------
__global__ __launch_bounds__(256) void attn2_kernel(const float* __restrict__ q,
                                                    const float* __restrict__ k,
                                                    const float* __restrict__ v,
                                                    const float* __restrict__ farsum,
                                                    const int* __restrict__ c0arr,
                                                    const float* __restrict__ ts,
                                                    const unsigned long long* __restrict__ bm,
                                                    const float* __restrict__ gamma,
                                                    float* __restrict__ out) {
  const int h = blockIdx.x;
  const int i0 = blockIdx.y * 64;
  const int b = blockIdx.z;
  __shared__ float Qs[64][68];   // transposed: Qs[d][i]
  __shared__ float KS[64][68];   // K transposed [d][j]; later aliased as S/P [i][j]
  __shared__ float Vs[64][68];   // natural: Vs[j][d]
  __shared__ float mrow[64], lrow[64], arow[64], Mband[64];
  __shared__ unsigned long long bmr[64];
  __shared__ int c0r[64];
  const int t = threadIdx.x, tx = t & 15, ty = t >> 4;

  // stage Q (transposed)
  for (int c = t; c < 1024; c += 256) {
    int r = c >> 4, d4 = (c & 15) << 2;
    float4 x = *(const float4*)(q + ((size_t)(b * S_) + i0 + r) * D_ + h * 64 + d4);
    Qs[d4 + 0][r] = x.x; Qs[d4 + 1][r] = x.y;
    Qs[d4 + 2][r] = x.z; Qs[d4 + 3][r] = x.w;
  }
  if (t < 64) {
    float delta = (float)t;
    float ld = logf(delta + 1.f);
    float cs = 0.f;
#pragma unroll
    for (int z = 0; z < NZ_; ++z) cs += cosf(gamma[z] * ld);
    Mband[t] = expf(-delta) * cs * 0.125f;    // fold 1/sqrt(DK)
    int grow = b * S_ + i0 + t;
    bmr[t] = bm[grow];
    int c0v = c0arr[grow];
    c0r[t] = c0v;
    mrow[t] = (c0v > 0) ? 0.f : -FLT_MAX;     // far scores are exactly 0
    lrow[t] = 0.f;
  }
  float accO[4][4] = {};

  for (int pass = 0; pass < 2; ++pass) {
    const int jt0 = i0 + (pass - 1) * 64;     // pass0: previous tile, pass1: diagonal
    if (jt0 < 0) continue;                    // uniform over block (blockIdx only)
    __syncthreads();                          // prior PV done with KS/Vs; Qs staged
    for (int c = t; c < 1024; c += 256) {
      int r = c >> 4, d4 = (c & 15) << 2;
      size_t base = ((size_t)(b * S_) + jt0 + r) * D_ + h * 64 + d4;
      float4 kx = *(const float4*)(k + base);
      KS[d4 + 0][r] = kx.x; KS[d4 + 1][r] = kx.y;
      KS[d4 + 2][r] = kx.z; KS[d4 + 3][r] = kx.w;
      *(float4*)&Vs[r][d4] = *(const float4*)(v + base);
    }
    __syncthreads();
    // S = Q * K^T  (64x64x64, 4x4 per thread)
    float accs[4][4] = {};
#pragma unroll 4
    for (int kk = 0; kk < 64; ++kk) {
      float4 aq = *(const float4*)&Qs[kk][ty << 2];
      float4 bk4 = *(const float4*)&KS[kk][tx << 2];
      const float av[4] = {aq.x, aq.y, aq.z, aq.w};
      const float bv[4] = {bk4.x, bk4.y, bk4.z, bk4.w};
#pragma unroll
      for (int i = 0; i < 4; ++i)
#pragma unroll
        for (int j = 0; j < 4; ++j) accs[i][j] += av[i] * bv[j];
    }
    __syncthreads();                          // done reading KS as K
    // write masked scores into KS (now S[i][j]); sentinel -FLT_MAX -> p = 0
#pragma unroll
    for (int i = 0; i < 4; ++i) {
      int il = (ty << 2) + i;
      unsigned long long bmv = bmr[il];
#pragma unroll
      for (int j = 0; j < 4; ++j) {
        int jl = (tx << 2) + j;
        int dlt = (pass == 0) ? (il + 64 - jl) : (il - jl);
        float s = -FLT_MAX;
        if (dlt >= 0 && dlt < 64 && ((bmv >> dlt) & 1ull))
          s = accs[i][j] * Mband[dlt];
        KS[il][jl] = s;
      }
    }
    __syncthreads();
    // online softmax: 4 threads per row
    {
      int row = t >> 2, q4 = t & 3;
      float* Sr = &KS[row][q4 << 4];
      float tmax = -FLT_MAX;
#pragma unroll
      for (int c = 0; c < 16; ++c) tmax = fmaxf(tmax, Sr[c]);
      tmax = fmaxf(tmax, __shfl_xor(tmax, 1));
      tmax = fmaxf(tmax, __shfl_xor(tmax, 2));
      float mold = mrow[row];
      float mnew = fmaxf(mold, tmax);
      if (q4 == 0) {
        arow[row] = expf(mold - mnew);        // mold=-FLT_MAX,finite mnew -> 0; both -> exp(0)=1
        mrow[row] = mnew;
      }
      float psum = 0.f;
#pragma unroll
      for (int c = 0; c < 16; ++c) {
        float s = Sr[c];
        float p = (s > -1e37f) ? expf(s - mnew) : 0.f;
        Sr[c] = p;
        psum += p;
      }
      psum += __shfl_xor(psum, 1);
      psum += __shfl_xor(psum, 2);
      if (q4 == 0) lrow[row] = lrow[row] * arow[row] + psum;
    }
    __syncthreads();
    // rescale O, then O += P * V
    float al[4];
#pragma unroll
    for (int i = 0; i < 4; ++i) al[i] = arow[(ty << 2) + i];
#pragma unroll
    for (int i = 0; i < 4; ++i)
#pragma unroll
      for (int j = 0; j < 4; ++j) accO[i][j] *= al[i];
    for (int kk = 0; kk < 64; kk += 4) {
      float4 pf4[4];
#pragma unroll
      for (int i = 0; i < 4; ++i) pf4[i] = *(const float4*)&KS[(ty << 2) + i][kk];
#pragma unroll
      for (int u = 0; u < 4; ++u) {
        float4 vf = *(const float4*)&Vs[kk + u][tx << 2];
        const float vv[4] = {vf.x, vf.y, vf.z, vf.w};
#pragma unroll
        for (int i = 0; i < 4; ++i) {
          float p = ((const float*)&pf4[i])[u];
          accO[i][0] += p * vv[0];
          accO[i][1] += p * vv[1];
          accO[i][2] += p * vv[2];
          accO[i][3] += p * vv[3];
        }
      }
    }
  }
  // epilogue: far contribution, degenerate uniform case, divide, store
#pragma unroll
  for (int i = 0; i < 4; ++i) {
    int il = (ty << 2) + i, gi = i0 + il;
    float m = mrow[il], l = lrow[il];
    int C0 = c0r[il];
    float efar = (C0 > 0) ? expf(-m) : 0.f;
    float denom = l + (float)C0 * efar;
    size_t base = ((size_t)(b * S_) + gi) * D_ + h * 64 + (tx << 2);
    float o0 = accO[i][0], o1 = accO[i][1], o2 = accO[i][2], o3 = accO[i][3];
    if (C0 > 0) {
      float4 f = *(const float4*)(farsum + base);
      o0 += efar * f.x; o1 += efar * f.y; o2 += efar * f.z; o3 += efar * f.w;
    }
    if (l == 0.f && C0 == 0) {
      // every causal position omega-masked: reference softmax is uniform 1/S
      // over ALL S positions -> out = mean over all v rows
      float s0 = 0.f, s1 = 0.f, s2 = 0.f, s3 = 0.f;
      for (int T = 0; T < NT_; ++T) {
        float4 tv = *(const float4*)(ts + ((size_t)(b * NT_) + T) * D_ + h * 64 + (tx << 2));
        s0 += tv.x; s1 += tv.y; s2 += tv.z; s3 += tv.w;
      }
      o0 = s0; o1 = s1; o2 = s2; o3 = s3;
      denom = (float)S_;
    }
    float inv = 1.f / denom;
    float4 o = make_float4(o0 * inv, o1 * inv, o2 * inv, o3 * inv);
    *(float4*)(out + base) = o;
  }
}

// ---------------------------------------------------------------------------
extern "C" void kernel_launch(void* const* d_in, const int* in_sizes, int n_in,
                              void* d_out, int out_size, void* d_ws, size_t ws_size,
                              hipStream_t stream) {
  const float* x     = (const float*)d_in[0];
  const float* wq    = (const float*)d_in[1];
  const float* bq    = (const float*)d_in[2];
  const float* wk    = (const float*)d_in[3];
  const float* bk    = (const float*)d_in[4];
  const float* wv    = (const float*)d_in[5];
  const float* bv    = (const float*)d_in[6];
  const float* wo    = (const float*)d_in[7];
  const float* bo    = (const float*)d_in[8];
  const float* omega = (const float*)d_in[9];
  const float* gamma = (const float*)d_in[10];
  const int*   ids   = (const int*)d_in[11];
  float* out = (float*)d_out;

  char* ws = (char*)d_ws;
  const size_t SZ = (size_t)B_ * S_ * D_ * sizeof(float);  // 16 MB
  float* q      = (float*)(ws);
  float* kbuf   = (float*)(ws + SZ);
  float* vbuf   = (float*)(ws + 2 * SZ);
  float* attno  = (float*)(ws + 3 * SZ);
  float* fsum   = (float*)(ws + 4 * SZ);
  float* ts     = (float*)(ws + 5 * SZ);
  char*  p6     = ws + 5 * SZ + (size_t)B_ * NT_ * D_ * sizeof(float);
  int*   c0     = (int*)p6;
  unsigned long long* bmask = (unsigned long long*)(p6 + (size_t)B_ * S_ * sizeof(int));

  dim3 gemmGrid(D_ / 64, (B_ * S_) / 64);
  gemm_bias<64, 64, 16><<<gemmGrid, 256, 0, stream>>>(x, wq, bq, q,    B_ * S_, D_, D_);
  gemm_bias<64, 64, 16><<<gemmGrid, 256, 0, stream>>>(x, wk, bk, kbuf, B_ * S_, D_, D_);
  gemm_bias<64, 64, 16><<<gemmGrid, 256, 0, stream>>>(x, wv, bv, vbuf, B_ * S_, D_, D_);
  tilesum_kernel<<<(B_ * NT_ * D_) / 256, 256, 0, stream>>>(vbuf, ts);
  bandmask_kernel<<<(B_ * S_) / 4, 256, 0, stream>>>(ids, omega, bmask);
  farsum_kernel<<<B_ * S_, 256, 0, stream>>>(vbuf, ts, ids, omega, fsum, c0);
  attn2_kernel<<<dim3(H_, S_ / 64, B_), 256, 0, stream>>>(q, kbuf, vbuf, fsum, c0, ts, bmask,
                                                          gamma, attno);
  gemm_bias<64, 64, 16><<<gemmGrid, 256, 0, stream>>>(attno, wo, bo, out, B_ * S_, D_, D_);
}

// Round 5
// 521.305 us; speedup vs baseline: 2.6394x; 1.9228x over previous
//
#include <hip/hip_runtime.h>
#include <math.h>
#include <float.h>

#define B_ 2
#define S_ 2048
#define D_ 1024
#define H_ 16
#define V_ 4096
#define NZ_ 10
#define NT_ 32            // S_/64 tiles of v rows
#define BS_ (B_ * S_)     // 4096 rows

typedef __attribute__((ext_vector_type(8))) __bf16 bf16x8;
typedef __attribute__((ext_vector_type(4))) float f32x4;

__device__ __forceinline__ unsigned short f2bf(float f) {
  unsigned u = __builtin_bit_cast(unsigned, f);
  u = (u + 0x7FFFu + ((u >> 16) & 1u)) >> 16;
  return (unsigned short)u;
}
__device__ __forceinline__ float bf2f(unsigned short h) {
  unsigned u = ((unsigned)h) << 16;
  return __builtin_bit_cast(float, u);
}

// ---------------------------------------------------------------------------
// fp32 -> bf16 hi (+ optional lo residual) split
// ---------------------------------------------------------------------------
template <bool WLO>
__global__ __launch_bounds__(256) void split_kernel(const float* __restrict__ in,
                                                    unsigned short* __restrict__ hi,
                                                    unsigned short* __restrict__ lo) {
  int i = (blockIdx.x * 256 + threadIdx.x) * 4;
  float4 x = *(const float4*)(in + i);
  ushort4 h;
  h.x = f2bf(x.x); h.y = f2bf(x.y); h.z = f2bf(x.z); h.w = f2bf(x.w);
  *(ushort4*)(hi + i) = h;
  if (WLO) {
    ushort4 l;
    l.x = f2bf(x.x - bf2f(h.x));
    l.y = f2bf(x.y - bf2f(h.y));
    l.z = f2bf(x.z - bf2f(h.z));
    l.w = f2bf(x.w - bf2f(h.w));
    *(ushort4*)(lo + i) = l;
  }
}

// ---------------------------------------------------------------------------
// MFMA GEMM: C[M,N] = A[M,K] * W[N,K]^T + bias[N]
// SPLIT=3: A ~ Ah+Al, W ~ Wh+Wl; C = Ah*Wh + Al*Wh + Ah*Wl (fp32-accurate)
// SPLIT=1: plain bf16.
// 128x128 tile, BK=32, global_load_lds(16B) staging, XOR-swizzled LDS slots.
// ---------------------------------------------------------------------------
template <int SPLIT>
__global__ __launch_bounds__(256) void mfma_gemm(const unsigned short* __restrict__ Ah,
                                                 const unsigned short* __restrict__ Al,
                                                 const unsigned short* __restrict__ Wh,
                                                 const unsigned short* __restrict__ Wl,
                                                 const float* __restrict__ bias,
                                                 float* __restrict__ C,
                                                 int M, int N, int K) {
  constexpr int NTILES = (SPLIT == 3) ? 4 : 2;
  __shared__ unsigned short tiles[NTILES * 4096];   // [tile][128 rows][32 cols]
  const int t = threadIdx.x;
  const int wave = t >> 6, lane = t & 63;
  const int i0 = blockIdx.y * 128, n0 = blockIdx.x * 128;
  const int wm = wave >> 1, wn = wave & 1;
  const int m = lane & 15, quad = lane >> 4;

  const unsigned short* gb[NTILES];
  gb[0] = Ah + (size_t)i0 * K;
  gb[1] = Wh + (size_t)n0 * K;
  if (SPLIT == 3) {
    gb[2] = Al + (size_t)i0 * K;
    gb[3] = Wl + (size_t)n0 * K;
  }

  f32x4 acc[4][4] = {};

  for (int k0 = 0; k0 < K; k0 += 32) {
    __syncthreads();     // all waves done reading LDS from previous iteration
    for (int cc = wave; cc < NTILES * 8; cc += 4) {
      int tile = cc >> 3, c = cc & 7;
      int s = (c << 6) + lane;                    // slot in [0,512)
      int row = s >> 2;
      int cq = (s & 3) ^ ((s >> 3) & 3);          // XOR swizzle of k-quad
      const unsigned short* g = gb[tile] + (size_t)row * K + k0 + (cq << 3);
      unsigned short* l = &tiles[tile * 4096 + (s << 3)];
      __builtin_amdgcn_global_load_lds((const __attribute__((address_space(1))) void*)g,
                                       (__attribute__((address_space(3))) void*)l,
                                       16, 0, 0);
    }
    __syncthreads();     // staging drained (compiler emits vmcnt(0))

    bf16x8 afh[4], bfh[4];
#pragma unroll
    for (int mt = 0; mt < 4; ++mt) {
      int r = wm * 64 + mt * 16 + m;
      afh[mt] = *(const bf16x8*)&tiles[0 * 4096 + r * 32 + ((quad ^ ((r >> 1) & 3)) << 3)];
    }
#pragma unroll
    for (int nt = 0; nt < 4; ++nt) {
      int r = wn * 64 + nt * 16 + m;
      bfh[nt] = *(const bf16x8*)&tiles[1 * 4096 + r * 32 + ((quad ^ ((r >> 1) & 3)) << 3)];
    }
    if (SPLIT == 3) {
      bf16x8 afl[4], bfl[4];
#pragma unroll
      for (int mt = 0; mt < 4; ++mt) {
        int r = wm * 64 + mt * 16 + m;
        afl[mt] = *(const bf16x8*)&tiles[2 * 4096 + r * 32 + ((quad ^ ((r >> 1) & 3)) << 3)];
      }
#pragma unroll
      for (int nt = 0; nt < 4; ++nt) {
        int r = wn * 64 + nt * 16 + m;
        bfl[nt] = *(const bf16x8*)&tiles[3 * 4096 + r * 32 + ((quad ^ ((r >> 1) & 3)) << 3)];
      }
#pragma unroll
      for (int mt = 0; mt < 4; ++mt)
#pragma unroll
        for (int nt = 0; nt < 4; ++nt) {
          acc[mt][nt] = __builtin_amdgcn_mfma_f32_16x16x32_bf16(afh[mt], bfh[nt], acc[mt][nt], 0, 0, 0);
          acc[mt][nt] = __builtin_amdgcn_mfma_f32_16x16x32_bf16(afl[mt], bfh[nt], acc[mt][nt], 0, 0, 0);
          acc[mt][nt] = __builtin_amdgcn_mfma_f32_16x16x32_bf16(afh[mt], bfl[nt], acc[mt][nt], 0, 0, 0);
        }
    } else {
#pragma unroll
      for (int mt = 0; mt < 4; ++mt)
#pragma unroll
        for (int nt = 0; nt < 4; ++nt)
          acc[mt][nt] = __builtin_amdgcn_mfma_f32_16x16x32_bf16(afh[mt], bfh[nt], acc[mt][nt], 0, 0, 0);
    }
  }

  // epilogue: C/D layout col=lane&15, row=quad*4+reg
  float bvv[4];
#pragma unroll
  for (int nt = 0; nt < 4; ++nt) bvv[nt] = bias[n0 + wn * 64 + nt * 16 + m];
#pragma unroll
  for (int mt = 0; mt < 4; ++mt) {
    int rbase = i0 + wm * 64 + mt * 16 + quad * 4;
#pragma unroll
    for (int nt = 0; nt < 4; ++nt) {
      int col = n0 + wn * 64 + nt * 16 + m;
#pragma unroll
      for (int r = 0; r < 4; ++r)
        C[(size_t)(rbase + r) * N + col] = acc[mt][nt][r] + bvv[nt];
    }
  }
}

// ---------------------------------------------------------------------------
// tilesum[b][T][d] = sum over j in [64T, 64T+64) of v[b][j][d]
// ---------------------------------------------------------------------------
__global__ void tilesum_kernel(const float* __restrict__ v, float* __restrict__ ts) {
  int idx = blockIdx.x * blockDim.x + threadIdx.x;
  int d = idx % D_;
  int bt = idx / D_;
  int T = bt % NT_;
  int b = bt / NT_;
  const float* p = v + (size_t)(b * S_ + T * 64) * D_ + d;
  float s = 0.f;
#pragma unroll 4
  for (int j = 0; j < 64; ++j) s += p[(size_t)j * D_];
  ts[idx] = s;
}

// ---------------------------------------------------------------------------
// bandmask[b*S+i] bit dlt = 1 iff j=i-dlt >= 0 and omega[id_i][id_j] != 0
// ---------------------------------------------------------------------------
__global__ __launch_bounds__(256) void bandmask_kernel(const int* __restrict__ ids,
                                                       const float* __restrict__ omega,
                                                       unsigned long long* __restrict__ bm) {
  int row = blockIdx.x * 4 + (threadIdx.x >> 6);
  int lane = threadIdx.x & 63;
  int b = row / S_, i = row % S_;
  int idi = ids[row];
  int j = i - lane;
  bool ok = false;
  if (j >= 0) ok = omega[(size_t)idi * V_ + ids[b * S_ + j]] != 0.f;
  unsigned long long mask = __ballot(ok);
  if (lane == 0) bm[row] = mask;
}

// ---------------------------------------------------------------------------
// farsum (bf16 out) / c0
// ---------------------------------------------------------------------------
__global__ __launch_bounds__(256) void farsum_kernel(const float* __restrict__ v,
                                                     const float* __restrict__ ts,
                                                     const int* __restrict__ ids,
                                                     const float* __restrict__ omega,
                                                     unsigned short* __restrict__ farsum,
                                                     int* __restrict__ c0) {
  const int b = blockIdx.x / S_;
  const int i = blockIdx.x % S_;
  const int t = threadIdx.x;
  if (i < 64) {
    if (t == 0) c0[blockIdx.x] = 0;
    return;
  }
  const int jmax = i - 64;
  const int F = jmax + 1;
  const int d0 = t * 4;
  float4 acc = make_float4(0.f, 0.f, 0.f, 0.f);
  const int nFull = F >> 6;
  for (int T = 0; T < nFull; ++T) {
    float4 x = *(const float4*)(ts + (size_t)(b * NT_ + T) * D_ + d0);
    acc.x += x.x; acc.y += x.y; acc.z += x.z; acc.w += x.w;
  }
  for (int j = nFull << 6; j <= jmax; ++j) {
    float4 x = *(const float4*)(v + (size_t)(b * S_ + j) * D_ + d0);
    acc.x += x.x; acc.y += x.y; acc.z += x.z; acc.w += x.w;
  }
  __shared__ int list[256];
  __shared__ int cnt;
  const int idi = ids[b * S_ + i];
  const float* omrow = omega + (size_t)idi * V_;
  int nmask = 0;
  for (int base = 0; base < F; base += 256) {
    if (t == 0) cnt = 0;
    __syncthreads();
    int j = base + t;
    if (j <= jmax) {
      int idj = ids[b * S_ + j];
      if (omrow[idj] == 0.f) list[atomicAdd(&cnt, 1)] = j;
    }
    __syncthreads();
    int c = cnt;
    nmask += c;
    for (int mm = 0; mm < c; ++mm) {
      int jm = list[mm];
      float4 x = *(const float4*)(v + (size_t)(b * S_ + jm) * D_ + d0);
      acc.x -= x.x; acc.y -= x.y; acc.z -= x.z; acc.w -= x.w;
    }
    __syncthreads();
  }
  ushort4 o;
  o.x = f2bf(acc.x); o.y = f2bf(acc.y); o.z = f2bf(acc.z); o.w = f2bf(acc.w);
  *(ushort4*)(farsum + (size_t)(b * S_ + i) * D_ + d0) = o;
  if (t == 0) c0[blockIdx.x] = F - nmask;
}

// ---------------------------------------------------------------------------
// Flash-style banded attention (fp32 compute), writes bf16 output for O-GEMM.
// ---------------------------------------------------------------------------
__global__ __launch_bounds__(256) void attn2_kernel(const float* __restrict__ q,
                                                    const float* __restrict__ k,
                                                    const float* __restrict__ v,
                                                    const unsigned short* __restrict__ farsum,
                                                    const int* __restrict__ c0arr,
                                                    const float* __restrict__ ts,
                                                    const unsigned long long* __restrict__ bm,
                                                    const float* __restrict__ gamma,
                                                    unsigned short* __restrict__ out) {
  const int h = blockIdx.x;
  const int i0 = blockIdx.y * 64;
  const int b = blockIdx.z;
  __shared__ float Qs[64][68];
  __shared__ float KS[64][68];
  __shared__ float Vs[64][68];
  __shared__ float mrow[64], lrow[64], arow[64], Mband[64];
  __shared__ unsigned long long bmr[64];
  __shared__ int c0r[64];
  const int t = threadIdx.x, tx = t & 15, ty = t >> 4;

  for (int c = t; c < 1024; c += 256) {
    int r = c >> 4, d4 = (c & 15) << 2;
    float4 x = *(const float4*)(q + ((size_t)(b * S_) + i0 + r) * D_ + h * 64 + d4);
    Qs[d4 + 0][r] = x.x; Qs[d4 + 1][r] = x.y;
    Qs[d4 + 2][r] = x.z; Qs[d4 + 3][r] = x.w;
  }
  if (t < 64) {
    float delta = (float)t;
    float ld = logf(delta + 1.f);
    float cs = 0.f;
#pragma unroll
    for (int z = 0; z < NZ_; ++z) cs += cosf(gamma[z] * ld);
    Mband[t] = expf(-delta) * cs * 0.125f;
    int grow = b * S_ + i0 + t;
    bmr[t] = bm[grow];
    int c0v = c0arr[grow];
    c0r[t] = c0v;
    mrow[t] = (c0v > 0) ? 0.f : -FLT_MAX;
    lrow[t] = 0.f;
  }
  float accO[4][4] = {};

  for (int pass = 0; pass < 2; ++pass) {
    const int jt0 = i0 + (pass - 1) * 64;
    if (jt0 < 0) continue;
    __syncthreads();
    for (int c = t; c < 1024; c += 256) {
      int r = c >> 4, d4 = (c & 15) << 2;
      size_t base = ((size_t)(b * S_) + jt0 + r) * D_ + h * 64 + d4;
      float4 kx = *(const float4*)(k + base);
      KS[d4 + 0][r] = kx.x; KS[d4 + 1][r] = kx.y;
      KS[d4 + 2][r] = kx.z; KS[d4 + 3][r] = kx.w;
      *(float4*)&Vs[r][d4] = *(const float4*)(v + base);
    }
    __syncthreads();
    float accs[4][4] = {};
#pragma unroll 4
    for (int kk = 0; kk < 64; ++kk) {
      float4 aq = *(const float4*)&Qs[kk][ty << 2];
      float4 bk4 = *(const float4*)&KS[kk][tx << 2];
      const float av[4] = {aq.x, aq.y, aq.z, aq.w};
      const float bv4[4] = {bk4.x, bk4.y, bk4.z, bk4.w};
#pragma unroll
      for (int i = 0; i < 4; ++i)
#pragma unroll
        for (int j = 0; j < 4; ++j) accs[i][j] += av[i] * bv4[j];
    }
    __syncthreads();
#pragma unroll
    for (int i = 0; i < 4; ++i) {
      int il = (ty << 2) + i;
      unsigned long long bmv = bmr[il];
#pragma unroll
      for (int j = 0; j < 4; ++j) {
        int jl = (tx << 2) + j;
        int dlt = (pass == 0) ? (il + 64 - jl) : (il - jl);
        float s = -FLT_MAX;
        if (dlt >= 0 && dlt < 64 && ((bmv >> dlt) & 1ull))
          s = accs[i][j] * Mband[dlt];
        KS[il][jl] = s;
      }
    }
    __syncthreads();
    {
      int row = t >> 2, q4 = t & 3;
      float* Sr = &KS[row][q4 << 4];
      float tmax = -FLT_MAX;
#pragma unroll
      for (int c = 0; c < 16; ++c) tmax = fmaxf(tmax, Sr[c]);
      tmax = fmaxf(tmax, __shfl_xor(tmax, 1));
      tmax = fmaxf(tmax, __shfl_xor(tmax, 2));
      float mold = mrow[row];
      float mnew = fmaxf(mold, tmax);
      if (q4 == 0) {
        arow[row] = expf(mold - mnew);
        mrow[row] = mnew;
      }
      float psum = 0.f;
#pragma unroll
      for (int c = 0; c < 16; ++c) {
        float s = Sr[c];
        float p = (s > -1e37f) ? expf(s - mnew) : 0.f;
        Sr[c] = p;
        psum += p;
      }
      psum += __shfl_xor(psum, 1);
      psum += __shfl_xor(psum, 2);
      if (q4 == 0) lrow[row] = lrow[row] * arow[row] + psum;
    }
    __syncthreads();
    float al[4];
#pragma unroll
    for (int i = 0; i < 4; ++i) al[i] = arow[(ty << 2) + i];
#pragma unroll
    for (int i = 0; i < 4; ++i)
#pragma unroll
      for (int j = 0; j < 4; ++j) accO[i][j] *= al[i];
    for (int kk = 0; kk < 64; kk += 4) {
      float4 pf4[4];
#pragma unroll
      for (int i = 0; i < 4; ++i) pf4[i] = *(const float4*)&KS[(ty << 2) + i][kk];
#pragma unroll
      for (int u = 0; u < 4; ++u) {
        float4 vf = *(const float4*)&Vs[kk + u][tx << 2];
        const float vv[4] = {vf.x, vf.y, vf.z, vf.w};
#pragma unroll
        for (int i = 0; i < 4; ++i) {
          float p = ((const float*)&pf4[i])[u];
          accO[i][0] += p * vv[0];
          accO[i][1] += p * vv[1];
          accO[i][2] += p * vv[2];
          accO[i][3] += p * vv[3];
        }
      }
    }
  }
#pragma unroll
  for (int i = 0; i < 4; ++i) {
    int il = (ty << 2) + i, gi = i0 + il;
    float m = mrow[il], l = lrow[il];
    int C0 = c0r[il];
    float efar = (C0 > 0) ? expf(-m) : 0.f;
    float denom = l + (float)C0 * efar;
    size_t base = ((size_t)(b * S_) + gi) * D_ + h * 64 + (tx << 2);
    float o0 = accO[i][0], o1 = accO[i][1], o2 = accO[i][2], o3 = accO[i][3];
    if (C0 > 0) {
      ushort4 f = *(const ushort4*)(farsum + base);
      o0 += efar * bf2f(f.x); o1 += efar * bf2f(f.y);
      o2 += efar * bf2f(f.z); o3 += efar * bf2f(f.w);
    }
    if (l == 0.f && C0 == 0) {
      float s0 = 0.f, s1 = 0.f, s2 = 0.f, s3 = 0.f;
      for (int T = 0; T < NT_; ++T) {
        float4 tv = *(const float4*)(ts + ((size_t)(b * NT_) + T) * D_ + h * 64 + (tx << 2));
        s0 += tv.x; s1 += tv.y; s2 += tv.z; s3 += tv.w;
      }
      o0 = s0; o1 = s1; o2 = s2; o3 = s3;
      denom = (float)S_;
    }
    float inv = 1.f / denom;
    ushort4 o;
    o.x = f2bf(o0 * inv); o.y = f2bf(o1 * inv);
    o.z = f2bf(o2 * inv); o.w = f2bf(o3 * inv);
    *(ushort4*)(out + base) = o;
  }
}

// ---------------------------------------------------------------------------
extern "C" void kernel_launch(void* const* d_in, const int* in_sizes, int n_in,
                              void* d_out, int out_size, void* d_ws, size_t ws_size,
                              hipStream_t stream) {
  const float* x     = (const float*)d_in[0];
  const float* wq    = (const float*)d_in[1];
  const float* bq    = (const float*)d_in[2];
  const float* wk    = (const float*)d_in[3];
  const float* bk    = (const float*)d_in[4];
  const float* wv    = (const float*)d_in[5];
  const float* bv    = (const float*)d_in[6];
  const float* wo    = (const float*)d_in[7];
  const float* bo    = (const float*)d_in[8];
  const float* omega = (const float*)d_in[9];
  const float* gamma = (const float*)d_in[10];
  const int*   ids   = (const int*)d_in[11];
  float* out = (float*)d_out;

  // Workspace layout: 71.6 MB total (kept under the 84 MB proven-safe mark;
  // R3's 96.8 MB layout corrupted harness memory -> post-timing divergence).
  char* ws = (char*)d_ws;
  const size_t SZF = (size_t)BS_ * D_ * sizeof(float);      // 16.78 MB
  const size_t SZH = SZF / 2;                               // 8.39 MB (bf16)
  const size_t WH  = (size_t)D_ * D_ * 2;                   // 2.10 MB
  float* q    = (float*)(ws);
  float* kbuf = (float*)(ws + SZF);
  float* vbuf = (float*)(ws + 2 * SZF);
  unsigned short* xl    = (unsigned short*)(ws + 3 * SZF);  // dies after K-GEMM
  unsigned short* fsumh = (unsigned short*)(ws + 3 * SZF);  // aliases xl (written later)
  unsigned short* xh    = (unsigned short*)(ws + 3 * SZF + SZH);
  unsigned short* ah    = xh;                               // attn out, after V-GEMM
  unsigned short* wbh   = (unsigned short*)(ws + 4 * SZF);  // per-phase weight hi
  unsigned short* wbl   = (unsigned short*)(ws + 4 * SZF + WH);
  float* ts = (float*)(ws + 4 * SZF + 2 * WH);
  int* c0 = (int*)((char*)ts + (size_t)B_ * NT_ * D_ * sizeof(float));
  unsigned long long* bmask = (unsigned long long*)((char*)c0 + (size_t)BS_ * sizeof(int));

  dim3 gg(D_ / 128, BS_ / 128);   // (8, 32)

  split_kernel<true><<<(BS_ * D_) / 1024, 256, 0, stream>>>(x, xh, xl);

  split_kernel<true><<<(D_ * D_) / 1024, 256, 0, stream>>>(wq, wbh, wbl);
  mfma_gemm<3><<<gg, 256, 0, stream>>>(xh, xl, wbh, wbl, bq, q, BS_, D_, D_);

  split_kernel<true><<<(D_ * D_) / 1024, 256, 0, stream>>>(wk, wbh, wbl);
  mfma_gemm<3><<<gg, 256, 0, stream>>>(xh, xl, wbh, wbl, bk, kbuf, BS_, D_, D_);

  split_kernel<false><<<(D_ * D_) / 1024, 256, 0, stream>>>(wv, wbh, nullptr);
  mfma_gemm<1><<<gg, 256, 0, stream>>>(xh, nullptr, wbh, nullptr, bv, vbuf, BS_, D_, D_);

  tilesum_kernel<<<(B_ * NT_ * D_) / 256, 256, 0, stream>>>(vbuf, ts);
  bandmask_kernel<<<(B_ * S_) / 4, 256, 0, stream>>>(ids, omega, bmask);
  farsum_kernel<<<B_ * S_, 256, 0, stream>>>(vbuf, ts, ids, omega, fsumh, c0);
  attn2_kernel<<<dim3(H_, S_ / 64, B_), 256, 0, stream>>>(q, kbuf, vbuf, fsumh, c0, ts, bmask,
                                                          gamma, ah);

  split_kernel<false><<<(D_ * D_) / 1024, 256, 0, stream>>>(wo, wbh, nullptr);
  mfma_gemm<1><<<gg, 256, 0, stream>>>(ah, nullptr, wbh, nullptr, bo, out, BS_, D_, D_);
}

// Round 6
// 464.718 us; speedup vs baseline: 2.9608x; 1.1218x over previous
//
#include <hip/hip_runtime.h>
#include <math.h>
#include <float.h>

#define B_ 2
#define S_ 2048
#define D_ 1024
#define H_ 16
#define V_ 4096
#define NZ_ 10
#define BS_ (B_ * S_)     // 4096 rows

typedef __attribute__((ext_vector_type(8))) __bf16 bf16x8;
typedef __attribute__((ext_vector_type(4))) float f32x4;

__device__ __forceinline__ unsigned short f2bf(float f) {
  unsigned u = __builtin_bit_cast(unsigned, f);
  u = (u + 0x7FFFu + ((u >> 16) & 1u)) >> 16;
  return (unsigned short)u;
}
__device__ __forceinline__ float bf2f(unsigned short h) {
  unsigned u = ((unsigned)h) << 16;
  return __builtin_bit_cast(float, u);
}

// ---------------------------------------------------------------------------
// fp32 -> bf16 hi (+ optional lo residual) split
// ---------------------------------------------------------------------------
template <bool WLO>
__global__ __launch_bounds__(256) void split_kernel(const float* __restrict__ in,
                                                    unsigned short* __restrict__ hi,
                                                    unsigned short* __restrict__ lo) {
  int i = (blockIdx.x * 256 + threadIdx.x) * 4;
  float4 x = *(const float4*)(in + i);
  ushort4 h;
  h.x = f2bf(x.x); h.y = f2bf(x.y); h.z = f2bf(x.z); h.w = f2bf(x.w);
  *(ushort4*)(hi + i) = h;
  if (WLO) {
    ushort4 l;
    l.x = f2bf(x.x - bf2f(h.x));
    l.y = f2bf(x.y - bf2f(h.y));
    l.z = f2bf(x.z - bf2f(h.z));
    l.w = f2bf(x.w - bf2f(h.w));
    *(ushort4*)(lo + i) = l;
  }
}

// ---------------------------------------------------------------------------
// MFMA GEMM: C[M,N] = A[M,K] * W[N,K]^T + bias[N]
// SPLIT=3: A ~ Ah+Al, W ~ Wh+Wl; C = Ah*Wh + Al*Wh + Ah*Wl (fp32-accurate)
// SPLIT=1: plain bf16. Optional secondary bf16 output Cbf.
// 128x128 tile, BK=32, global_load_lds(16B) staging, XOR-swizzled LDS slots.
// ---------------------------------------------------------------------------
template <int SPLIT>
__global__ __launch_bounds__(256) void mfma_gemm(const unsigned short* __restrict__ Ah,
                                                 const unsigned short* __restrict__ Al,
                                                 const unsigned short* __restrict__ Wh,
                                                 const unsigned short* __restrict__ Wl,
                                                 const float* __restrict__ bias,
                                                 float* __restrict__ C,
                                                 unsigned short* __restrict__ Cbf,
                                                 int M, int N, int K) {
  constexpr int NTILES = (SPLIT == 3) ? 4 : 2;
  __shared__ unsigned short tiles[NTILES * 4096];   // [tile][128 rows][32 cols]
  const int t = threadIdx.x;
  const int wave = t >> 6, lane = t & 63;
  const int i0 = blockIdx.y * 128, n0 = blockIdx.x * 128;
  const int wm = wave >> 1, wn = wave & 1;
  const int m = lane & 15, quad = lane >> 4;

  const unsigned short* gb[NTILES];
  gb[0] = Ah + (size_t)i0 * K;
  gb[1] = Wh + (size_t)n0 * K;
  if (SPLIT == 3) {
    gb[2] = Al + (size_t)i0 * K;
    gb[3] = Wl + (size_t)n0 * K;
  }

  f32x4 acc[4][4] = {};

  for (int k0 = 0; k0 < K; k0 += 32) {
    __syncthreads();     // all waves done reading LDS from previous iteration
    for (int cc = wave; cc < NTILES * 8; cc += 4) {
      int tile = cc >> 3, c = cc & 7;
      int s = (c << 6) + lane;                    // slot in [0,512)
      int row = s >> 2;
      int cq = (s & 3) ^ ((s >> 3) & 3);          // XOR swizzle of k-quad
      const unsigned short* g = gb[tile] + (size_t)row * K + k0 + (cq << 3);
      unsigned short* l = &tiles[tile * 4096 + (s << 3)];
      __builtin_amdgcn_global_load_lds((const __attribute__((address_space(1))) void*)g,
                                       (__attribute__((address_space(3))) void*)l,
                                       16, 0, 0);
    }
    __syncthreads();     // staging drained (compiler emits vmcnt(0))

    bf16x8 afh[4], bfh[4];
#pragma unroll
    for (int mt = 0; mt < 4; ++mt) {
      int r = wm * 64 + mt * 16 + m;
      afh[mt] = *(const bf16x8*)&tiles[0 * 4096 + r * 32 + ((quad ^ ((r >> 1) & 3)) << 3)];
    }
#pragma unroll
    for (int nt = 0; nt < 4; ++nt) {
      int r = wn * 64 + nt * 16 + m;
      bfh[nt] = *(const bf16x8*)&tiles[1 * 4096 + r * 32 + ((quad ^ ((r >> 1) & 3)) << 3)];
    }
    if (SPLIT == 3) {
      bf16x8 afl[4], bfl[4];
#pragma unroll
      for (int mt = 0; mt < 4; ++mt) {
        int r = wm * 64 + mt * 16 + m;
        afl[mt] = *(const bf16x8*)&tiles[2 * 4096 + r * 32 + ((quad ^ ((r >> 1) & 3)) << 3)];
      }
#pragma unroll
      for (int nt = 0; nt < 4; ++nt) {
        int r = wn * 64 + nt * 16 + m;
        bfl[nt] = *(const bf16x8*)&tiles[3 * 4096 + r * 32 + ((quad ^ ((r >> 1) & 3)) << 3)];
      }
#pragma unroll
      for (int mt = 0; mt < 4; ++mt)
#pragma unroll
        for (int nt = 0; nt < 4; ++nt) {
          acc[mt][nt] = __builtin_amdgcn_mfma_f32_16x16x32_bf16(afh[mt], bfh[nt], acc[mt][nt], 0, 0, 0);
          acc[mt][nt] = __builtin_amdgcn_mfma_f32_16x16x32_bf16(afl[mt], bfh[nt], acc[mt][nt], 0, 0, 0);
          acc[mt][nt] = __builtin_amdgcn_mfma_f32_16x16x32_bf16(afh[mt], bfl[nt], acc[mt][nt], 0, 0, 0);
        }
    } else {
#pragma unroll
      for (int mt = 0; mt < 4; ++mt)
#pragma unroll
        for (int nt = 0; nt < 4; ++nt)
          acc[mt][nt] = __builtin_amdgcn_mfma_f32_16x16x32_bf16(afh[mt], bfh[nt], acc[mt][nt], 0, 0, 0);
    }
  }

  // epilogue: C/D layout col=lane&15, row=quad*4+reg
  float bvv[4];
#pragma unroll
  for (int nt = 0; nt < 4; ++nt) bvv[nt] = bias[n0 + wn * 64 + nt * 16 + m];
#pragma unroll
  for (int mt = 0; mt < 4; ++mt) {
    int rbase = i0 + wm * 64 + mt * 16 + quad * 4;
#pragma unroll
    for (int nt = 0; nt < 4; ++nt) {
      int col = n0 + wn * 64 + nt * 16 + m;
#pragma unroll
      for (int r = 0; r < 4; ++r) {
        float val = acc[mt][nt][r] + bvv[nt];
        C[(size_t)(rbase + r) * N + col] = val;
        if (Cbf) Cbf[(size_t)(rbase + r) * N + col] = f2bf(val);
      }
    }
  }
}

// ---------------------------------------------------------------------------
// ts8[b][g][d] = sum over j in [8g, 8g+8) of v[b][j][d]   (g in [0,256))
// ---------------------------------------------------------------------------
__global__ void ts8_kernel(const float* __restrict__ v, float* __restrict__ ts8) {
  int idx = blockIdx.x * blockDim.x + threadIdx.x;  // (b*256+g)*D_ + d
  int d = idx % D_;
  int bg = idx / D_;
  int g = bg % 256;
  int b = bg / 256;
  const float* p = v + (size_t)(b * S_ + g * 8) * D_ + d;
  float s = 0.f;
#pragma unroll
  for (int j = 0; j < 8; ++j) s += p[(size_t)j * D_];
  ts8[idx] = s;
}

// ---------------------------------------------------------------------------
// tsp[b][T][d] = sum of v rows j < 64T  (T in [0,32]; T=32 is the total sum)
// ---------------------------------------------------------------------------
__global__ __launch_bounds__(256) void tsp_kernel(const float* __restrict__ ts8,
                                                  float* __restrict__ tsp) {
  int b = blockIdx.x >> 2;
  int d = ((blockIdx.x & 3) << 8) + threadIdx.x;
  float run = 0.f;
  for (int T = 0; T < 32; ++T) {
    tsp[((size_t)b * 33 + T) * D_ + d] = run;
#pragma unroll
    for (int u = 0; u < 8; ++u)
      run += ts8[((size_t)b * 256 + T * 8 + u) * D_ + d];
  }
  tsp[((size_t)b * 33 + 32) * D_ + d] = run;
}

// ---------------------------------------------------------------------------
// bandmask[b*S+i] bit dlt = 1 iff j=i-dlt >= 0 and omega[id_i][id_j] != 0
// ---------------------------------------------------------------------------
__global__ __launch_bounds__(256) void bandmask_kernel(const int* __restrict__ ids,
                                                       const float* __restrict__ omega,
                                                       unsigned long long* __restrict__ bm) {
  int row = blockIdx.x * 4 + (threadIdx.x >> 6);
  int lane = threadIdx.x & 63;
  int b = row / S_, i = row % S_;
  int idi = ids[row];
  int j = i - lane;
  bool ok = false;
  if (j >= 0) ok = omega[(size_t)idi * V_ + ids[b * S_ + j]] != 0.f;
  unsigned long long mask = __ballot(ok);
  if (lane == 0) bm[row] = mask;
}

// ---------------------------------------------------------------------------
// farsum (bf16 out) / c0 — prefix-hierarchy version:
// main part = tsp[T] + up to 7 ts8 groups + up to 7 bf16 tail rows,
// then subtract the rare omega-masked rows (bf16 reads).
// ---------------------------------------------------------------------------
__global__ __launch_bounds__(256) void farsum_kernel(const unsigned short* __restrict__ vh,
                                                     const float* __restrict__ ts8,
                                                     const float* __restrict__ tsp,
                                                     const int* __restrict__ ids,
                                                     const float* __restrict__ omega,
                                                     unsigned short* __restrict__ farsum,
                                                     int* __restrict__ c0) {
  const int b = blockIdx.x / S_;
  const int i = blockIdx.x % S_;
  const int t = threadIdx.x;
  if (i < 64) {
    if (t == 0) c0[blockIdx.x] = 0;
    return;
  }
  const int jmax = i - 64;
  const int F = jmax + 1;
  const int d0 = t * 4;
  const int T = F >> 6;          // full 64-row tiles
  const int G8 = (F & 63) >> 3;  // full 8-row groups in the partial tile

  float4 acc = *(const float4*)(tsp + ((size_t)b * 33 + T) * D_ + d0);
  for (int u = 0; u < G8; ++u) {
    float4 x = *(const float4*)(ts8 + ((size_t)b * 256 + T * 8 + u) * D_ + d0);
    acc.x += x.x; acc.y += x.y; acc.z += x.z; acc.w += x.w;
  }
  for (int j = (T << 6) + (G8 << 3); j <= jmax; ++j) {
    ushort4 x = *(const ushort4*)(vh + ((size_t)(b * S_) + j) * D_ + d0);
    acc.x += bf2f(x.x); acc.y += bf2f(x.y);
    acc.z += bf2f(x.z); acc.w += bf2f(x.w);
  }

  __shared__ int list[256];
  __shared__ int cnt;
  const int idi = ids[b * S_ + i];
  const float* omrow = omega + (size_t)idi * V_;
  int nmask = 0;
  for (int base = 0; base < F; base += 256) {
    if (t == 0) cnt = 0;
    __syncthreads();
    int j = base + t;
    if (j <= jmax) {
      int idj = ids[b * S_ + j];
      if (omrow[idj] == 0.f) list[atomicAdd(&cnt, 1)] = j;
    }
    __syncthreads();
    int c = cnt;
    nmask += c;
    for (int mm = 0; mm < c; ++mm) {
      int jm = list[mm];
      ushort4 x = *(const ushort4*)(vh + ((size_t)(b * S_) + jm) * D_ + d0);
      acc.x -= bf2f(x.x); acc.y -= bf2f(x.y);
      acc.z -= bf2f(x.z); acc.w -= bf2f(x.w);
    }
    __syncthreads();
  }
  ushort4 o;
  o.x = f2bf(acc.x); o.y = f2bf(acc.y); o.z = f2bf(acc.z); o.w = f2bf(acc.w);
  *(ushort4*)(farsum + (size_t)(b * S_ + i) * D_ + d0) = o;
  if (t == 0) c0[blockIdx.x] = F - nmask;
}

// ---------------------------------------------------------------------------
// Flash-style banded attention (fp32 compute), writes bf16 output for O-GEMM.
// ---------------------------------------------------------------------------
__global__ __launch_bounds__(256) void attn2_kernel(const float* __restrict__ q,
                                                    const float* __restrict__ k,
                                                    const float* __restrict__ v,
                                                    const unsigned short* __restrict__ farsum,
                                                    const int* __restrict__ c0arr,
                                                    const float* __restrict__ tsp,
                                                    const unsigned long long* __restrict__ bm,
                                                    const float* __restrict__ gamma,
                                                    unsigned short* __restrict__ out) {
  const int h = blockIdx.x;
  const int i0 = blockIdx.y * 64;
  const int b = blockIdx.z;
  __shared__ float Qs[64][68];
  __shared__ float KS[64][68];
  __shared__ float Vs[64][68];
  __shared__ float mrow[64], lrow[64], arow[64], Mband[64];
  __shared__ unsigned long long bmr[64];
  __shared__ int c0r[64];
  const int t = threadIdx.x, tx = t & 15, ty = t >> 4;

  for (int c = t; c < 1024; c += 256) {
    int r = c >> 4, d4 = (c & 15) << 2;
    float4 x = *(const float4*)(q + ((size_t)(b * S_) + i0 + r) * D_ + h * 64 + d4);
    Qs[d4 + 0][r] = x.x; Qs[d4 + 1][r] = x.y;
    Qs[d4 + 2][r] = x.z; Qs[d4 + 3][r] = x.w;
  }
  if (t < 64) {
    float delta = (float)t;
    float ld = logf(delta + 1.f);
    float cs = 0.f;
#pragma unroll
    for (int z = 0; z < NZ_; ++z) cs += cosf(gamma[z] * ld);
    Mband[t] = expf(-delta) * cs * 0.125f;
    int grow = b * S_ + i0 + t;
    bmr[t] = bm[grow];
    int c0v = c0arr[grow];
    c0r[t] = c0v;
    mrow[t] = (c0v > 0) ? 0.f : -FLT_MAX;
    lrow[t] = 0.f;
  }
  float accO[4][4] = {};

  for (int pass = 0; pass < 2; ++pass) {
    const int jt0 = i0 + (pass - 1) * 64;
    if (jt0 < 0) continue;
    __syncthreads();
    for (int c = t; c < 1024; c += 256) {
      int r = c >> 4, d4 = (c & 15) << 2;
      size_t base = ((size_t)(b * S_) + jt0 + r) * D_ + h * 64 + d4;
      float4 kx = *(const float4*)(k + base);
      KS[d4 + 0][r] = kx.x; KS[d4 + 1][r] = kx.y;
      KS[d4 + 2][r] = kx.z; KS[d4 + 3][r] = kx.w;
      *(float4*)&Vs[r][d4] = *(const float4*)(v + base);
    }
    __syncthreads();
    float accs[4][4] = {};
#pragma unroll 4
    for (int kk = 0; kk < 64; ++kk) {
      float4 aq = *(const float4*)&Qs[kk][ty << 2];
      float4 bk4 = *(const float4*)&KS[kk][tx << 2];
      const float av[4] = {aq.x, aq.y, aq.z, aq.w};
      const float bv4[4] = {bk4.x, bk4.y, bk4.z, bk4.w};
#pragma unroll
      for (int i = 0; i < 4; ++i)
#pragma unroll
        for (int j = 0; j < 4; ++j) accs[i][j] += av[i] * bv4[j];
    }
    __syncthreads();
#pragma unroll
    for (int i = 0; i < 4; ++i) {
      int il = (ty << 2) + i;
      unsigned long long bmv = bmr[il];
#pragma unroll
      for (int j = 0; j < 4; ++j) {
        int jl = (tx << 2) + j;
        int dlt = (pass == 0) ? (il + 64 - jl) : (il - jl);
        float s = -FLT_MAX;
        if (dlt >= 0 && dlt < 64 && ((bmv >> dlt) & 1ull))
          s = accs[i][j] * Mband[dlt];
        KS[il][jl] = s;
      }
    }
    __syncthreads();
    {
      int row = t >> 2, q4 = t & 3;
      float* Sr = &KS[row][q4 << 4];
      float tmax = -FLT_MAX;
#pragma unroll
      for (int c = 0; c < 16; ++c) tmax = fmaxf(tmax, Sr[c]);
      tmax = fmaxf(tmax, __shfl_xor(tmax, 1));
      tmax = fmaxf(tmax, __shfl_xor(tmax, 2));
      float mold = mrow[row];
      float mnew = fmaxf(mold, tmax);
      if (q4 == 0) {
        arow[row] = expf(mold - mnew);
        mrow[row] = mnew;
      }
      float psum = 0.f;
#pragma unroll
      for (int c = 0; c < 16; ++c) {
        float s = Sr[c];
        float p = (s > -1e37f) ? expf(s - mnew) : 0.f;
        Sr[c] = p;
        psum += p;
      }
      psum += __shfl_xor(psum, 1);
      psum += __shfl_xor(psum, 2);
      if (q4 == 0) lrow[row] = lrow[row] * arow[row] + psum;
    }
    __syncthreads();
    float al[4];
#pragma unroll
    for (int i = 0; i < 4; ++i) al[i] = arow[(ty << 2) + i];
#pragma unroll
    for (int i = 0; i < 4; ++i)
#pragma unroll
      for (int j = 0; j < 4; ++j) accO[i][j] *= al[i];
    for (int kk = 0; kk < 64; kk += 4) {
      float4 pf4[4];
#pragma unroll
      for (int i = 0; i < 4; ++i) pf4[i] = *(const float4*)&KS[(ty << 2) + i][kk];
#pragma unroll
      for (int u = 0; u < 4; ++u) {
        float4 vf = *(const float4*)&Vs[kk + u][tx << 2];
        const float vv[4] = {vf.x, vf.y, vf.z, vf.w};
#pragma unroll
        for (int i = 0; i < 4; ++i) {
          float p = ((const float*)&pf4[i])[u];
          accO[i][0] += p * vv[0];
          accO[i][1] += p * vv[1];
          accO[i][2] += p * vv[2];
          accO[i][3] += p * vv[3];
        }
      }
    }
  }
#pragma unroll
  for (int i = 0; i < 4; ++i) {
    int il = (ty << 2) + i, gi = i0 + il;
    float m = mrow[il], l = lrow[il];
    int C0 = c0r[il];
    float efar = (C0 > 0) ? expf(-m) : 0.f;
    float denom = l + (float)C0 * efar;
    size_t base = ((size_t)(b * S_) + gi) * D_ + h * 64 + (tx << 2);
    float o0 = accO[i][0], o1 = accO[i][1], o2 = accO[i][2], o3 = accO[i][3];
    if (C0 > 0) {
      ushort4 f = *(const ushort4*)(farsum + base);
      o0 += efar * bf2f(f.x); o1 += efar * bf2f(f.y);
      o2 += efar * bf2f(f.z); o3 += efar * bf2f(f.w);
    }
    if (l == 0.f && C0 == 0) {
      // all causal positions masked -> uniform 1/S over ALL rows
      float4 tv = *(const float4*)(tsp + ((size_t)b * 33 + 32) * D_ + h * 64 + (tx << 2));
      o0 = tv.x; o1 = tv.y; o2 = tv.z; o3 = tv.w;
      denom = (float)S_;
    }
    float inv = 1.f / denom;
    ushort4 o;
    o.x = f2bf(o0 * inv); o.y = f2bf(o1 * inv);
    o.z = f2bf(o2 * inv); o.w = f2bf(o3 * inv);
    *(ushort4*)(out + base) = o;
  }
}

// ---------------------------------------------------------------------------
extern "C" void kernel_launch(void* const* d_in, const int* in_sizes, int n_in,
                              void* d_out, int out_size, void* d_ws, size_t ws_size,
                              hipStream_t stream) {
  const float* x     = (const float*)d_in[0];
  const float* wq    = (const float*)d_in[1];
  const float* bq    = (const float*)d_in[2];
  const float* wk    = (const float*)d_in[3];
  const float* bk    = (const float*)d_in[4];
  const float* wv    = (const float*)d_in[5];
  const float* bv    = (const float*)d_in[6];
  const float* wo    = (const float*)d_in[7];
  const float* bo    = (const float*)d_in[8];
  const float* omega = (const float*)d_in[9];
  const float* gamma = (const float*)d_in[10];
  const int*   ids   = (const int*)d_in[11];
  float* out = (float*)d_out;

  // Workspace: ~82 MB (keep below the 84 MB proven-safe watermark; 96.8 MB
  // corrupted harness memory in R3).
  char* ws = (char*)d_ws;
  const size_t SZF = (size_t)BS_ * D_ * sizeof(float);      // 16.78 MB
  const size_t SZH = SZF / 2;                               // 8.39 MB (bf16)
  const size_t WH  = (size_t)D_ * D_ * 2;                   // 2.10 MB
  float* q    = (float*)(ws);
  float* kbuf = (float*)(ws + SZF);
  float* vbuf = (float*)(ws + 2 * SZF);
  unsigned short* xl    = (unsigned short*)(ws + 3 * SZF);  // dies after K-GEMM
  unsigned short* fsumh = (unsigned short*)(ws + 3 * SZF);  // aliases xl
  unsigned short* xh    = (unsigned short*)(ws + 3 * SZF + SZH);
  unsigned short* ah    = xh;                               // attn out, after V-GEMM
  unsigned short* vh    = (unsigned short*)(ws + 4 * SZF);  // bf16 v mirror
  unsigned short* wbh   = (unsigned short*)(ws + 4 * SZF + SZH);
  unsigned short* wbl   = (unsigned short*)(ws + 4 * SZF + SZH + WH);
  char* tail = ws + 4 * SZF + SZH + 2 * WH;
  float* ts8 = (float*)tail;                                          // 2.10 MB
  float* tsp = (float*)(tail + (size_t)B_ * 256 * D_ * sizeof(float)); // 0.27 MB
  int* c0 = (int*)((char*)tsp + (size_t)B_ * 33 * D_ * sizeof(float));
  unsigned long long* bmask = (unsigned long long*)((char*)c0 + (size_t)BS_ * sizeof(int));

  dim3 gg(D_ / 128, BS_ / 128);   // (8, 32)

  split_kernel<true><<<(BS_ * D_) / 1024, 256, 0, stream>>>(x, xh, xl);

  split_kernel<true><<<(D_ * D_) / 1024, 256, 0, stream>>>(wq, wbh, wbl);
  mfma_gemm<3><<<gg, 256, 0, stream>>>(xh, xl, wbh, wbl, bq, q, nullptr, BS_, D_, D_);

  split_kernel<true><<<(D_ * D_) / 1024, 256, 0, stream>>>(wk, wbh, wbl);
  mfma_gemm<3><<<gg, 256, 0, stream>>>(xh, xl, wbh, wbl, bk, kbuf, nullptr, BS_, D_, D_);

  split_kernel<false><<<(D_ * D_) / 1024, 256, 0, stream>>>(wv, wbh, nullptr);
  mfma_gemm<1><<<gg, 256, 0, stream>>>(xh, nullptr, wbh, nullptr, bv, vbuf, vh, BS_, D_, D_);

  ts8_kernel<<<(B_ * 256 * D_) / 256, 256, 0, stream>>>(vbuf, ts8);
  tsp_kernel<<<B_ * 4, 256, 0, stream>>>(ts8, tsp);
  bandmask_kernel<<<(B_ * S_) / 4, 256, 0, stream>>>(ids, omega, bmask);
  farsum_kernel<<<B_ * S_, 256, 0, stream>>>(vh, ts8, tsp, ids, omega, fsumh, c0);
  attn2_kernel<<<dim3(H_, S_ / 64, B_), 256, 0, stream>>>(q, kbuf, vbuf, fsumh, c0, tsp, bmask,
                                                          gamma, ah);

  split_kernel<false><<<(D_ * D_) / 1024, 256, 0, stream>>>(wo, wbh, nullptr);
  mfma_gemm<1><<<gg, 256, 0, stream>>>(ah, nullptr, wbh, nullptr, bo, out, nullptr, BS_, D_, D_);
}

// Round 8
// 454.800 us; speedup vs baseline: 3.0254x; 1.0218x over previous
//
#include <hip/hip_runtime.h>
#include <math.h>
#include <float.h>

#define B_ 2
#define S_ 2048
#define D_ 1024
#define H_ 16
#define V_ 4096
#define NZ_ 10
#define BS_ (B_ * S_)     // 4096 rows

typedef __attribute__((ext_vector_type(8))) __bf16 bf16x8;
typedef __attribute__((ext_vector_type(4))) float f32x4;

#define MFMA16(a, b, c) __builtin_amdgcn_mfma_f32_16x16x32_bf16((a), (b), (c), 0, 0, 0)

__device__ __forceinline__ unsigned short f2bf(float f) {
  unsigned u = __builtin_bit_cast(unsigned, f);
  u = (u + 0x7FFFu + ((u >> 16) & 1u)) >> 16;
  return (unsigned short)u;
}
__device__ __forceinline__ float bf2f(unsigned short h) {
  unsigned u = ((unsigned)h) << 16;
  return __builtin_bit_cast(float, u);
}

// ---------------------------------------------------------------------------
// fp32 -> bf16 hi (+ optional lo residual) split
// ---------------------------------------------------------------------------
template <bool WLO>
__global__ __launch_bounds__(256) void split_kernel(const float* __restrict__ in,
                                                    unsigned short* __restrict__ hi,
                                                    unsigned short* __restrict__ lo) {
  int i = (blockIdx.x * 256 + threadIdx.x) * 4;
  float4 x = *(const float4*)(in + i);
  ushort4 h;
  h.x = f2bf(x.x); h.y = f2bf(x.y); h.z = f2bf(x.z); h.w = f2bf(x.w);
  *(ushort4*)(hi + i) = h;
  if (WLO) {
    ushort4 l;
    l.x = f2bf(x.x - bf2f(h.x));
    l.y = f2bf(x.y - bf2f(h.y));
    l.z = f2bf(x.z - bf2f(h.z));
    l.w = f2bf(x.w - bf2f(h.w));
    *(ushort4*)(lo + i) = l;
  }
}

// ---------------------------------------------------------------------------
// MFMA GEMM: C[M,N] = A[M,K] * W[N,K]^T + bias[N]
// SPLIT=3: hi/lo split inputs (fp32-accurate). SPLIT=1: plain bf16.
// Outputs (each optional): C fp32, Chi bf16, Clo bf16 residual (needs Chi).
// 128x128 tile, BK=32, global_load_lds(16B) staging, XOR-swizzled LDS slots.
// ---------------------------------------------------------------------------
template <int SPLIT>
__global__ __launch_bounds__(256) void mfma_gemm(const unsigned short* __restrict__ Ah,
                                                 const unsigned short* __restrict__ Al,
                                                 const unsigned short* __restrict__ Wh,
                                                 const unsigned short* __restrict__ Wl,
                                                 const float* __restrict__ bias,
                                                 float* __restrict__ C,
                                                 unsigned short* __restrict__ Chi,
                                                 unsigned short* __restrict__ Clo,
                                                 int M, int N, int K) {
  constexpr int NTILES = (SPLIT == 3) ? 4 : 2;
  __shared__ unsigned short tiles[NTILES * 4096];   // [tile][128 rows][32 cols]
  const int t = threadIdx.x;
  const int wave = t >> 6, lane = t & 63;
  const int i0 = blockIdx.y * 128, n0 = blockIdx.x * 128;
  const int wm = wave >> 1, wn = wave & 1;
  const int m = lane & 15, quad = lane >> 4;

  const unsigned short* gb[NTILES];
  gb[0] = Ah + (size_t)i0 * K;
  gb[1] = Wh + (size_t)n0 * K;
  if (SPLIT == 3) {
    gb[2] = Al + (size_t)i0 * K;
    gb[3] = Wl + (size_t)n0 * K;
  }

  f32x4 acc[4][4] = {};

  for (int k0 = 0; k0 < K; k0 += 32) {
    __syncthreads();     // all waves done reading LDS from previous iteration
    for (int cc = wave; cc < NTILES * 8; cc += 4) {
      int tile = cc >> 3, c = cc & 7;
      int s = (c << 6) + lane;                    // slot in [0,512)
      int row = s >> 2;
      int cq = (s & 3) ^ ((s >> 3) & 3);          // XOR swizzle of k-quad
      const unsigned short* g = gb[tile] + (size_t)row * K + k0 + (cq << 3);
      unsigned short* l = &tiles[tile * 4096 + (s << 3)];
      __builtin_amdgcn_global_load_lds((const __attribute__((address_space(1))) void*)g,
                                       (__attribute__((address_space(3))) void*)l,
                                       16, 0, 0);
    }
    __syncthreads();     // staging drained (compiler emits vmcnt(0))

    bf16x8 afh[4], bfh[4];
#pragma unroll
    for (int mt = 0; mt < 4; ++mt) {
      int r = wm * 64 + mt * 16 + m;
      afh[mt] = *(const bf16x8*)&tiles[0 * 4096 + r * 32 + ((quad ^ ((r >> 1) & 3)) << 3)];
    }
#pragma unroll
    for (int nt = 0; nt < 4; ++nt) {
      int r = wn * 64 + nt * 16 + m;
      bfh[nt] = *(const bf16x8*)&tiles[1 * 4096 + r * 32 + ((quad ^ ((r >> 1) & 3)) << 3)];
    }
    if (SPLIT == 3) {
      bf16x8 afl[4], bfl[4];
#pragma unroll
      for (int mt = 0; mt < 4; ++mt) {
        int r = wm * 64 + mt * 16 + m;
        afl[mt] = *(const bf16x8*)&tiles[2 * 4096 + r * 32 + ((quad ^ ((r >> 1) & 3)) << 3)];
      }
#pragma unroll
      for (int nt = 0; nt < 4; ++nt) {
        int r = wn * 64 + nt * 16 + m;
        bfl[nt] = *(const bf16x8*)&tiles[3 * 4096 + r * 32 + ((quad ^ ((r >> 1) & 3)) << 3)];
      }
#pragma unroll
      for (int mt = 0; mt < 4; ++mt)
#pragma unroll
        for (int nt = 0; nt < 4; ++nt) {
          acc[mt][nt] = MFMA16(afh[mt], bfh[nt], acc[mt][nt]);
          acc[mt][nt] = MFMA16(afl[mt], bfh[nt], acc[mt][nt]);
          acc[mt][nt] = MFMA16(afh[mt], bfl[nt], acc[mt][nt]);
        }
    } else {
#pragma unroll
      for (int mt = 0; mt < 4; ++mt)
#pragma unroll
        for (int nt = 0; nt < 4; ++nt)
          acc[mt][nt] = MFMA16(afh[mt], bfh[nt], acc[mt][nt]);
    }
  }

  // epilogue: C/D layout col=lane&15, row=quad*4+reg
  float bvv[4];
#pragma unroll
  for (int nt = 0; nt < 4; ++nt) bvv[nt] = bias[n0 + wn * 64 + nt * 16 + m];
#pragma unroll
  for (int mt = 0; mt < 4; ++mt) {
    int rbase = i0 + wm * 64 + mt * 16 + quad * 4;
#pragma unroll
    for (int nt = 0; nt < 4; ++nt) {
      int col = n0 + wn * 64 + nt * 16 + m;
#pragma unroll
      for (int r = 0; r < 4; ++r) {
        float val = acc[mt][nt][r] + bvv[nt];
        size_t idx = (size_t)(rbase + r) * N + col;
        if (C) C[idx] = val;
        if (Chi) {
          unsigned short hv = f2bf(val);
          Chi[idx] = hv;
          if (Clo) Clo[idx] = f2bf(val - bf2f(hv));
        }
      }
    }
  }
}

// ---------------------------------------------------------------------------
// ts8[b][g][d] = sum over j in [8g, 8g+8) of v[b][j][d]   (g in [0,256))
// ---------------------------------------------------------------------------
__global__ void ts8_kernel(const float* __restrict__ v, float* __restrict__ ts8) {
  int idx = blockIdx.x * blockDim.x + threadIdx.x;  // (b*256+g)*D_ + d
  int d = idx % D_;
  int bg = idx / D_;
  int g = bg % 256;
  int b = bg / 256;
  const float* p = v + (size_t)(b * S_ + g * 8) * D_ + d;
  float s = 0.f;
#pragma unroll
  for (int j = 0; j < 8; ++j) s += p[(size_t)j * D_];
  ts8[idx] = s;
}

// ---------------------------------------------------------------------------
// tsp[b][T][d] = sum of v rows j < 64T  (T in [0,32]; T=32 is the total sum)
// ---------------------------------------------------------------------------
__global__ __launch_bounds__(256) void tsp_kernel(const float* __restrict__ ts8,
                                                  float* __restrict__ tsp) {
  int b = blockIdx.x >> 2;
  int d = ((blockIdx.x & 3) << 8) + threadIdx.x;
  float run = 0.f;
  for (int T = 0; T < 32; ++T) {
    tsp[((size_t)b * 33 + T) * D_ + d] = run;
#pragma unroll
    for (int u = 0; u < 8; ++u)
      run += ts8[((size_t)b * 256 + T * 8 + u) * D_ + d];
  }
  tsp[((size_t)b * 33 + 32) * D_ + d] = run;
}

// ---------------------------------------------------------------------------
// bandmask[b*S+i] bit dlt = 1 iff j=i-dlt >= 0 and omega[id_i][id_j] != 0
// ---------------------------------------------------------------------------
__global__ __launch_bounds__(256) void bandmask_kernel(const int* __restrict__ ids,
                                                       const float* __restrict__ omega,
                                                       unsigned long long* __restrict__ bm) {
  int row = blockIdx.x * 4 + (threadIdx.x >> 6);
  int lane = threadIdx.x & 63;
  int b = row / S_, i = row % S_;
  int idi = ids[row];
  int j = i - lane;
  bool ok = false;
  if (j >= 0) ok = omega[(size_t)idi * V_ + ids[b * S_ + j]] != 0.f;
  unsigned long long mask = __ballot(ok);
  if (lane == 0) bm[row] = mask;
}

// ---------------------------------------------------------------------------
// farsum (bf16 out) / c0 — prefix-hierarchy version
// ---------------------------------------------------------------------------
__global__ __launch_bounds__(256) void farsum_kernel(const unsigned short* __restrict__ vh,
                                                     const float* __restrict__ ts8,
                                                     const float* __restrict__ tsp,
                                                     const int* __restrict__ ids,
                                                     const float* __restrict__ omega,
                                                     unsigned short* __restrict__ farsum,
                                                     int* __restrict__ c0) {
  const int b = blockIdx.x / S_;
  const int i = blockIdx.x % S_;
  const int t = threadIdx.x;
  if (i < 64) {
    if (t == 0) c0[blockIdx.x] = 0;
    return;
  }
  const int jmax = i - 64;
  const int F = jmax + 1;
  const int d0 = t * 4;
  const int T = F >> 6;          // full 64-row tiles
  const int G8 = (F & 63) >> 3;  // full 8-row groups in the partial tile

  float4 acc = *(const float4*)(tsp + ((size_t)b * 33 + T) * D_ + d0);
  for (int u = 0; u < G8; ++u) {
    float4 x = *(const float4*)(ts8 + ((size_t)b * 256 + T * 8 + u) * D_ + d0);
    acc.x += x.x; acc.y += x.y; acc.z += x.z; acc.w += x.w;
  }
  for (int j = (T << 6) + (G8 << 3); j <= jmax; ++j) {
    ushort4 x = *(const ushort4*)(vh + ((size_t)(b * S_) + j) * D_ + d0);
    acc.x += bf2f(x.x); acc.y += bf2f(x.y);
    acc.z += bf2f(x.z); acc.w += bf2f(x.w);
  }

  __shared__ int list[256];
  __shared__ int cnt;
  const int idi = ids[b * S_ + i];
  const float* omrow = omega + (size_t)idi * V_;
  int nmask = 0;
  for (int base = 0; base < F; base += 256) {
    if (t == 0) cnt = 0;
    __syncthreads();
    int j = base + t;
    if (j <= jmax) {
      int idj = ids[b * S_ + j];
      if (omrow[idj] == 0.f) list[atomicAdd(&cnt, 1)] = j;
    }
    __syncthreads();
    int c = cnt;
    nmask += c;
    for (int mm = 0; mm < c; ++mm) {
      int jm = list[mm];
      ushort4 x = *(const ushort4*)(vh + ((size_t)(b * S_) + jm) * D_ + d0);
      acc.x -= bf2f(x.x); acc.y -= bf2f(x.y);
      acc.z -= bf2f(x.z); acc.w -= bf2f(x.w);
    }
    __syncthreads();
  }
  ushort4 o;
  o.x = f2bf(acc.x); o.y = f2bf(acc.y); o.z = f2bf(acc.z); o.w = f2bf(acc.w);
  *(ushort4*)(farsum + (size_t)(b * S_ + i) * D_ + d0) = o;
  if (t == 0) c0[blockIdx.x] = F - nmask;
}

// ---------------------------------------------------------------------------
// MFMA flash-style banded attention.
// QK^T: hi/lo bf16 split (3 MFMAs) for fp32-level score accuracy.
// P: bf16 in LDS (aliases Kl buffer); PV: plain bf16 MFMA with V^T in LDS.
// Per wave: 2x2 of 16x16 tiles. Row stride 72 (bf16) -> 2-way-only conflicts.
// LDS ~47.8 KB -> 3 blocks/CU.
// ---------------------------------------------------------------------------
__global__ __launch_bounds__(256) void attn3_kernel(
    const unsigned short* __restrict__ qh, const unsigned short* __restrict__ ql,
    const unsigned short* __restrict__ kh, const unsigned short* __restrict__ kl,
    const unsigned short* __restrict__ vh, const unsigned short* __restrict__ farsum,
    const int* __restrict__ c0arr, const float* __restrict__ tsp,
    const unsigned long long* __restrict__ bm, const float* __restrict__ gamma,
    unsigned short* __restrict__ out) {
  const int h = blockIdx.x, i0 = blockIdx.y * 64, b = blockIdx.z;
  __shared__ unsigned short Qhs[64][72], Qls[64][72], Khs[64][72], KlP[64][72], Vt[64][72];
  __shared__ float mrow[64], lrow[64], arow[64], Mband[64];
  __shared__ float rmaxw[4][32], rsumw[4][32];
  __shared__ unsigned long long bmr[64];
  __shared__ int c0r[64];
  const int t = threadIdx.x, lane = t & 63, wave = t >> 6;
  const int m = lane & 15, quad = lane >> 4;
  const int wm = wave >> 1, wn = wave & 1;

  // stage Q hi/lo (once)
  for (int c = t; c < 1024; c += 256) {
    int r = c >> 4, d4 = (c & 15) << 2;
    size_t g = ((size_t)(b * S_) + i0 + r) * D_ + h * 64 + d4;
    *(ushort4*)&Qhs[r][d4] = *(const ushort4*)(qh + g);
    *(ushort4*)&Qls[r][d4] = *(const ushort4*)(ql + g);
  }
  if (t < 64) {
    float delta = (float)t;
    float ld = logf(delta + 1.f);
    float cs = 0.f;
#pragma unroll
    for (int z = 0; z < NZ_; ++z) cs += cosf(gamma[z] * ld);
    Mband[t] = expf(-delta) * cs * 0.125f;
    int grow = b * S_ + i0 + t;
    bmr[t] = bm[grow];
    int c0v = c0arr[grow];
    c0r[t] = c0v;
    mrow[t] = (c0v > 0) ? 0.f : -FLT_MAX;
    lrow[t] = 0.f;
  }
  f32x4 accO[2][2] = {};

  for (int pass = 0; pass < 2; ++pass) {
    const int jt0 = i0 + (pass - 1) * 64;
    if (jt0 < 0) continue;
    __syncthreads();                 // prev PV done (and Q/init staged, pass0)
    for (int c = t; c < 1024; c += 256) {
      int r = c >> 4, d4 = (c & 15) << 2;
      size_t g = ((size_t)(b * S_) + jt0 + r) * D_ + h * 64 + d4;
      *(ushort4*)&Khs[r][d4] = *(const ushort4*)(kh + g);
      *(ushort4*)&KlP[r][d4] = *(const ushort4*)(kl + g);
      ushort4 vv = *(const ushort4*)(vh + g);
      Vt[d4 + 0][r] = vv.x; Vt[d4 + 1][r] = vv.y;
      Vt[d4 + 2][r] = vv.z; Vt[d4 + 3][r] = vv.w;
    }
    __syncthreads();
    // S = Q K^T (hi/lo split)
    f32x4 accS[2][2] = {};
#pragma unroll
    for (int kc = 0; kc < 2; ++kc) {
      bf16x8 aH[2], aL[2], bH[2], bL[2];
#pragma unroll
      for (int mt = 0; mt < 2; ++mt) {
        aH[mt] = *(const bf16x8*)&Qhs[wm * 32 + mt * 16 + m][kc * 32 + quad * 8];
        aL[mt] = *(const bf16x8*)&Qls[wm * 32 + mt * 16 + m][kc * 32 + quad * 8];
      }
#pragma unroll
      for (int nt = 0; nt < 2; ++nt) {
        bH[nt] = *(const bf16x8*)&Khs[wn * 32 + nt * 16 + m][kc * 32 + quad * 8];
        bL[nt] = *(const bf16x8*)&KlP[wn * 32 + nt * 16 + m][kc * 32 + quad * 8];
      }
#pragma unroll
      for (int mt = 0; mt < 2; ++mt)
#pragma unroll
        for (int nt = 0; nt < 2; ++nt) {
          accS[mt][nt] = MFMA16(aH[mt], bH[nt], accS[mt][nt]);
          accS[mt][nt] = MFMA16(aL[mt], bH[nt], accS[mt][nt]);
          accS[mt][nt] = MFMA16(aH[mt], bL[nt], accS[mt][nt]);
        }
    }
    // mask + per-row max (C/D layout: row=quad*4+r, col=lane&15)
    float rmx[2][4];
#pragma unroll
    for (int mt = 0; mt < 2; ++mt)
#pragma unroll
      for (int r = 0; r < 4; ++r) rmx[mt][r] = -FLT_MAX;
#pragma unroll
    for (int mt = 0; mt < 2; ++mt)
#pragma unroll
      for (int nt = 0; nt < 2; ++nt)
#pragma unroll
        for (int r = 0; r < 4; ++r) {
          int il = wm * 32 + mt * 16 + quad * 4 + r;
          int jl = wn * 32 + nt * 16 + m;
          int dlt = (pass == 0) ? (il + 64 - jl) : (il - jl);
          float s = -FLT_MAX;
          if (dlt >= 0 && dlt < 64 && ((bmr[il] >> dlt) & 1ull))
            s = accS[mt][nt][r] * Mband[dlt];
          accS[mt][nt][r] = s;
          rmx[mt][r] = fmaxf(rmx[mt][r], s);
        }
#pragma unroll
    for (int off = 1; off < 16; off <<= 1)
#pragma unroll
      for (int mt = 0; mt < 2; ++mt)
#pragma unroll
        for (int r = 0; r < 4; ++r)
          rmx[mt][r] = fmaxf(rmx[mt][r], __shfl_xor(rmx[mt][r], off));
    if (m == 0)
#pragma unroll
      for (int mt = 0; mt < 2; ++mt)
#pragma unroll
        for (int r = 0; r < 4; ++r)
          rmaxw[wave][mt * 16 + quad * 4 + r] = rmx[mt][r];
    __syncthreads();
    if (t < 64) {
      int wmw = t >> 5, idx = t & 31;
      float tmax = fmaxf(rmaxw[wmw * 2][idx], rmaxw[wmw * 2 + 1][idx]);
      float mold = mrow[t], mnew = fmaxf(mold, tmax);
      arow[t] = expf(mold - mnew);   // both -FLT_MAX -> exp(0)=1 (lrow stays 0)
      mrow[t] = mnew;
    }
    __syncthreads();
    // P (bf16, into KlP — Kl is dead past the QK barrier) + row sums (fp32)
    float rs[2][4] = {};
#pragma unroll
    for (int mt = 0; mt < 2; ++mt)
#pragma unroll
      for (int nt = 0; nt < 2; ++nt)
#pragma unroll
        for (int r = 0; r < 4; ++r) {
          int il = wm * 32 + mt * 16 + quad * 4 + r;
          int jl = wn * 32 + nt * 16 + m;
          float s = accS[mt][nt][r];
          float p = (s > -1e37f) ? expf(s - mrow[il]) : 0.f;
          rs[mt][r] += p;
          KlP[il][jl] = f2bf(p);
        }
#pragma unroll
    for (int off = 1; off < 16; off <<= 1)
#pragma unroll
      for (int mt = 0; mt < 2; ++mt)
#pragma unroll
        for (int r = 0; r < 4; ++r)
          rs[mt][r] += __shfl_xor(rs[mt][r], off);
    if (m == 0)
#pragma unroll
      for (int mt = 0; mt < 2; ++mt)
#pragma unroll
        for (int r = 0; r < 4; ++r)
          rsumw[wave][mt * 16 + quad * 4 + r] = rs[mt][r];
    // rescale O by alpha (arow valid since last barrier)
#pragma unroll
    for (int mt = 0; mt < 2; ++mt)
#pragma unroll
      for (int r = 0; r < 4; ++r) {
        float al = arow[wm * 32 + mt * 16 + quad * 4 + r];
        accO[mt][0][r] *= al;
        accO[mt][1][r] *= al;
      }
    __syncthreads();                 // P + rsumw visible
    if (t < 64) {
      int wmw = t >> 5, idx = t & 31;
      lrow[t] = lrow[t] * arow[t] + rsumw[wmw * 2][idx] + rsumw[wmw * 2 + 1][idx];
    }
    // O += P V   (A = P[i][j], B = V^T[d][j])
#pragma unroll
    for (int kc = 0; kc < 2; ++kc) {
      bf16x8 aP[2], bV[2];
#pragma unroll
      for (int mt = 0; mt < 2; ++mt)
        aP[mt] = *(const bf16x8*)&KlP[wm * 32 + mt * 16 + m][kc * 32 + quad * 8];
#pragma unroll
      for (int nt = 0; nt < 2; ++nt)
        bV[nt] = *(const bf16x8*)&Vt[wn * 32 + nt * 16 + m][kc * 32 + quad * 8];
#pragma unroll
      for (int mt = 0; mt < 2; ++mt)
#pragma unroll
        for (int nt = 0; nt < 2; ++nt)
          accO[mt][nt] = MFMA16(aP[mt], bV[nt], accO[mt][nt]);
    }
  }
  __syncthreads();                   // final lrow update visible
  // epilogue
#pragma unroll
  for (int mt = 0; mt < 2; ++mt)
#pragma unroll
    for (int r = 0; r < 4; ++r) {
      int il = wm * 32 + mt * 16 + quad * 4 + r;
      int gi = i0 + il;
      float mv = mrow[il], l = lrow[il];
      int C0 = c0r[il];
      float efar = (C0 > 0) ? expf(-mv) : 0.f;
      float denom = l + (float)C0 * efar;
      bool degen = (l == 0.f && C0 == 0);
      if (degen) denom = (float)S_;
      float inv = 1.f / denom;
#pragma unroll
      for (int nt = 0; nt < 2; ++nt) {
        int d = wn * 32 + nt * 16 + m;
        size_t base = ((size_t)(b * S_) + gi) * D_ + h * 64 + d;
        float o = accO[mt][nt][r];
        if (C0 > 0) o += efar * bf2f(farsum[base]);
        if (degen) o = tsp[((size_t)b * 33 + 32) * D_ + h * 64 + d];
        out[base] = f2bf(o * inv);
      }
    }
}

// ---------------------------------------------------------------------------
extern "C" void kernel_launch(void* const* d_in, const int* in_sizes, int n_in,
                              void* d_out, int out_size, void* d_ws, size_t ws_size,
                              hipStream_t stream) {
  const float* x     = (const float*)d_in[0];
  const float* wq    = (const float*)d_in[1];
  const float* bq    = (const float*)d_in[2];
  const float* wk    = (const float*)d_in[3];
  const float* bk    = (const float*)d_in[4];
  const float* wv    = (const float*)d_in[5];
  const float* bv    = (const float*)d_in[6];
  const float* wo    = (const float*)d_in[7];
  const float* bo    = (const float*)d_in[8];
  const float* omega = (const float*)d_in[9];
  const float* gamma = (const float*)d_in[10];
  const int*   ids   = (const int*)d_in[11];
  float* out = (float*)d_out;

  // Workspace ~82 MB (keep below the 84 MB proven-safe watermark; 96.8 MB
  // corrupted harness memory in R3).
  char* ws = (char*)d_ws;
  const size_t SZH = (size_t)BS_ * D_ * 2;                  // 8.39 MB bf16 unit
  const size_t WH  = (size_t)D_ * D_ * 2;                   // 2.10 MB
  unsigned short* qhb = (unsigned short*)(ws);
  unsigned short* qlb = (unsigned short*)(ws + 1 * SZH);
  unsigned short* khb = (unsigned short*)(ws + 2 * SZH);
  unsigned short* klb = (unsigned short*)(ws + 3 * SZH);
  float*          vbuf = (float*)(ws + 4 * SZH);            // 2 units (fp32)
  unsigned short* vhb = (unsigned short*)(ws + 6 * SZH);
  unsigned short* xl    = (unsigned short*)(ws + 7 * SZH);  // dies after K-GEMM
  unsigned short* fsumh = xl;                               // aliases xl
  unsigned short* xh    = (unsigned short*)(ws + 8 * SZH);
  unsigned short* ah    = xh;                               // attn out, after V-GEMM
  unsigned short* wbh   = (unsigned short*)(ws + 9 * SZH);
  unsigned short* wbl   = (unsigned short*)(ws + 9 * SZH + WH);
  char* tail = ws + 9 * SZH + 2 * WH;
  float* ts8 = (float*)tail;                                          // 2.10 MB
  float* tsp = (float*)(tail + (size_t)B_ * 256 * D_ * sizeof(float)); // 0.27 MB
  int* c0 = (int*)((char*)tsp + (size_t)B_ * 33 * D_ * sizeof(float));
  unsigned long long* bmask = (unsigned long long*)((char*)c0 + (size_t)BS_ * sizeof(int));

  dim3 gg(D_ / 128, BS_ / 128);   // (8, 32)

  split_kernel<true><<<(BS_ * D_) / 1024, 256, 0, stream>>>(x, xh, xl);

  split_kernel<true><<<(D_ * D_) / 1024, 256, 0, stream>>>(wq, wbh, wbl);
  mfma_gemm<3><<<gg, 256, 0, stream>>>(xh, xl, wbh, wbl, bq, nullptr, qhb, qlb, BS_, D_, D_);

  split_kernel<true><<<(D_ * D_) / 1024, 256, 0, stream>>>(wk, wbh, wbl);
  mfma_gemm<3><<<gg, 256, 0, stream>>>(xh, xl, wbh, wbl, bk, nullptr, khb, klb, BS_, D_, D_);

  split_kernel<false><<<(D_ * D_) / 1024, 256, 0, stream>>>(wv, wbh, nullptr);
  mfma_gemm<1><<<gg, 256, 0, stream>>>(xh, nullptr, wbh, nullptr, bv, vbuf, vhb, nullptr,
                                       BS_, D_, D_);

  ts8_kernel<<<(B_ * 256 * D_) / 256, 256, 0, stream>>>(vbuf, ts8);
  tsp_kernel<<<B_ * 4, 256, 0, stream>>>(ts8, tsp);
  bandmask_kernel<<<(B_ * S_) / 4, 256, 0, stream>>>(ids, omega, bmask);
  farsum_kernel<<<B_ * S_, 256, 0, stream>>>(vhb, ts8, tsp, ids, omega, fsumh, c0);
  attn3_kernel<<<dim3(H_, S_ / 64, B_), 256, 0, stream>>>(qhb, qlb, khb, klb, vhb, fsumh, c0,
                                                          tsp, bmask, gamma, ah);

  split_kernel<false><<<(D_ * D_) / 1024, 256, 0, stream>>>(wo, wbh, nullptr);
  mfma_gemm<1><<<gg, 256, 0, stream>>>(ah, nullptr, wbh, nullptr, bo, out, nullptr, nullptr,
                                       BS_, D_, D_);
}